// Round 3
// baseline (1230.961 us; speedup 1.0000x reference)
//
#include <hip/hip_runtime.h>

#pragma clang fp contract(off)

#define HH 256
#define WW 256
#define NVERTS 6890
#define NFACES 13776
#define RASTN (NFACES + 1)          // +1 sentinel face (depth=BIG, never wins)
#define LISTSTRIDE 14080            // >= ((NFACES+255)&~255) = 13824
#define BIGF 1000000000.0f
#define EPSF 1e-8f
#define RCHUNK 256

// c(i) = ((i+0.5)/256)*2 - 1  -- exact in f32, matches reference pixel coords
__device__ __forceinline__ float pixc(int i) {
    return __fsub_rn(__fmul_rn(__fdiv_rn(__fadd_rn((float)i, 0.5f), 256.0f), 2.0f), 1.0f);
}

// ---------------------------------------------------------------------------
// Kernel 1: per (b, face) precompute (+ sentinel at f == NFACES).
// rast[idx*3+0] = {x2, y2, A, B}
// rast[idx*3+1] = {C, D, inv, 0}
// rast[idx*3+2] = {z0, z1, z2, face_id_bits}
// Degenerate (|denom|<EPS) and sentinel: w0=w1=0, w2=1, depth=BIG exact
// -> never wins the strict-< z-test, identical to ref's inside &= |denom|>=EPS.
// ---------------------------------------------------------------------------
__global__ __launch_bounds__(256) void precompute_kernel(
    const float* __restrict__ src_cam, const float* __restrict__ src_verts,
    const float* __restrict__ tgt_cam, const float* __restrict__ tgt_verts,
    const int* __restrict__ faces,
    float4* __restrict__ rast, float4* __restrict__ flowg, int B)
{
    int idx = blockIdx.x * blockDim.x + threadIdx.x;
    if (idx >= B * RASTN) return;
    int b = idx / RASTN;
    int f = idx - b * RASTN;
    float4* rr = rast + ((size_t)b * RASTN + f) * 3;
    if (f == NFACES) {   // sentinel
        rr[0] = make_float4(0.0f, 0.0f, 0.0f, 0.0f);
        rr[1] = make_float4(0.0f, 0.0f, 1.0f, 0.0f);
        rr[2] = make_float4(BIGF, BIGF, BIGF, __int_as_float(-1));
        return;
    }
    int i0 = faces[3*f+0], i1 = faces[3*f+1], i2 = faces[3*f+2];

    float tc0 = tgt_cam[3*b+0], tc1 = tgt_cam[3*b+1], tc2 = tgt_cam[3*b+2];
    const float* tv = tgt_verts + (size_t)b * NVERTS * 3;
    float x0 = __fmul_rn(tc0, __fadd_rn(tv[3*i0+0], tc1));
    float y0 = -__fmul_rn(tc0, __fadd_rn(tv[3*i0+1], tc2));
    float z0 = tv[3*i0+2];
    float x1 = __fmul_rn(tc0, __fadd_rn(tv[3*i1+0], tc1));
    float y1 = -__fmul_rn(tc0, __fadd_rn(tv[3*i1+1], tc2));
    float z1 = tv[3*i1+2];
    float x2 = __fmul_rn(tc0, __fadd_rn(tv[3*i2+0], tc1));
    float y2 = -__fmul_rn(tc0, __fadd_rn(tv[3*i2+1], tc2));
    float z2 = tv[3*i2+2];

    float A  = __fsub_rn(y1, y2);
    float D  = __fsub_rn(x0, x2);
    float Bc = __fsub_rn(x2, x1);
    float E  = __fsub_rn(y0, y2);
    float denom = __fadd_rn(__fmul_rn(A, D), __fmul_rn(Bc, E));
    bool valid = (fabsf(denom) >= EPSF);
    float inv = __fdiv_rn(1.0f, valid ? denom : 1.0f);
    float Cc = __fsub_rn(y2, y0);

    if (valid) {
        rr[0] = make_float4(x2, y2, A, Bc);
        rr[1] = make_float4(Cc, D, inv, 0.0f);
        rr[2] = make_float4(z0, z1, z2, __int_as_float(f));
    } else {
        rr[0] = make_float4(0.0f, 0.0f, 0.0f, 0.0f);
        rr[1] = make_float4(0.0f, 0.0f, 1.0f, 0.0f);
        rr[2] = make_float4(BIGF, BIGF, BIGF, __int_as_float(f));
    }

    float sc0 = src_cam[3*b+0], sc1 = src_cam[3*b+1], sc2 = src_cam[3*b+2];
    const float* sv = src_verts + (size_t)b * NVERTS * 3;
    float g0x = __fmul_rn(sc0, __fadd_rn(sv[3*i0+0], sc1));
    float g0y = __fmul_rn(sc0, __fadd_rn(sv[3*i0+1], sc2));
    float g1x = __fmul_rn(sc0, __fadd_rn(sv[3*i1+0], sc1));
    float g1y = __fmul_rn(sc0, __fadd_rn(sv[3*i1+1], sc2));
    float g2x = __fmul_rn(sc0, __fadd_rn(sv[3*i2+0], sc1));
    float g2y = __fmul_rn(sc0, __fadd_rn(sv[3*i2+1], sc2));
    size_t fo = ((size_t)b * NFACES + f) * 2;
    flowg[fo+0] = make_float4(g0x, g0y, g1x, g1y);
    flowg[fo+1] = make_float4(g2x, g2y, 0.0f, 0.0f);
}

// ---------------------------------------------------------------------------
// Kernel 2: per-tile face lists, ONE WAVE per (b,tile), barrier-free ordered
// ballot compaction (ascending face order preserved -> tie-break correctness).
// Interval-arithmetic cull with 1e-6-relative rounding margins: conservative
// even for sliver faces. List padded to a multiple of RCHUNK with the
// sentinel face index NFACES; counts[] stores the padded count.
// ---------------------------------------------------------------------------
__global__ __launch_bounds__(64) void bin_kernel(
    const float4* __restrict__ rast, int* __restrict__ lists,
    int* __restrict__ counts, int B)
{
    int tile = blockIdx.x;          // 0..255
    int b = blockIdx.y;
    int tX = tile & 15, tY = tile >> 4;
    float txmin = pixc(tX * 16), txmax = pixc(tX * 16 + 15);
    float tymin = pixc(tY * 16), tymax = pixc(tY * 16 + 15);

    int lane = threadIdx.x;
    const float4* rb = rast + (size_t)b * RASTN * 3;
    int* mylist = lists + ((size_t)b * 256 + tile) * LISTSTRIDE;
    int total = 0;

    for (int base = 0; base < NFACES; base += 64) {
        int f = base + lane;
        bool pass = false;
        if (f < NFACES) {
            float4 r0 = rb[(size_t)f*3+0];
            float4 r1 = rb[(size_t)f*3+1];
            float dx0 = txmin - r0.x, dx1 = txmax - r0.x;
            float dy0 = tymin - r0.y, dy1 = tymax - r0.y;
            float mx = fmaxf(fabsf(dx0), fabsf(dx1));
            float my = fmaxf(fabsf(dy0), fabsf(dy1));
            float inv = r1.z, ainv = fabsf(inv);
            float t0max = fmaxf(r0.z*dx0, r0.z*dx1) + fmaxf(r0.w*dy0, r0.w*dy1);
            float t0min = fminf(r0.z*dx0, r0.z*dx1) + fminf(r0.w*dy0, r0.w*dy1);
            float w0max = fmaxf(t0max*inv, t0min*inv);
            float w0min = fminf(t0max*inv, t0min*inv);
            float am0 = fabsf(r0.z)*mx + fabsf(r0.w)*my;
            float M0 = 1e-6f * (am0*ainv + 1.0f + fmaxf(fabsf(w0max), fabsf(w0min)));
            float t1max = fmaxf(r1.x*dx0, r1.x*dx1) + fmaxf(r1.y*dy0, r1.y*dy1);
            float t1min = fminf(r1.x*dx0, r1.x*dx1) + fminf(r1.y*dy0, r1.y*dy1);
            float w1max = fmaxf(t1max*inv, t1min*inv);
            float w1min = fminf(t1max*inv, t1min*inv);
            float am1 = fabsf(r1.x)*mx + fabsf(r1.y)*my;
            float M1 = 1e-6f * (am1*ainv + 1.0f + fmaxf(fabsf(w1max), fabsf(w1min)));
            float M2 = M0 + M1 + 1e-6f * (1.0f + fabsf(w0min) + fabsf(w1min));
            float w2max = 1.0f - w0min - w1min + M2;
            pass = (w0max + M0 >= 0.0f) && (w1max + M1 >= 0.0f) && (w2max >= 0.0f);
        }
        unsigned long long m = __ballot(pass);
        if (pass) {
            int pre = __popcll(m & ((1ull << lane) - 1ull));
            mylist[total + pre] = f;
        }
        total += __popcll(m);
    }
    int nfp = (total + RCHUNK - 1) & ~(RCHUNK - 1);
    for (int idx = total + lane; idx < nfp; idx += 64) mylist[idx] = NFACES;
    if (lane == 0) counts[b * 256 + tile] = nfp;
}

// ---------------------------------------------------------------------------
// Kernel 3: raster + flow + grid sample. 128 threads = 16x8 pixel half-tile
// (2 waves). 256-face chunks staged to SoA LDS once per block; chunk k+1
// globally prefetched into registers while computing chunk k. Inner loop:
// fixed 256 trip (sentinel padding), 4 INDEPENDENT z-buffer chains (faces
// j%4==c) merged exactly by lexicographic (depth, face index) — identical
// semantics to the reference's first-argmin + strict-< scan, but breaks the
// serial dependency for ILP. All depth-path math `_rn`, no FMA contraction.
// ---------------------------------------------------------------------------
__global__ __launch_bounds__(128) void raster_kernel(
    const float4* __restrict__ rast, const float4* __restrict__ flowg,
    const int* __restrict__ lists, const int* __restrict__ counts,
    const float* __restrict__ src_img, float* __restrict__ out, int B)
{
    __shared__ float4 sR0[RCHUNK], sR1[RCHUNK], sR2[RCHUNK];
    int t = threadIdx.x;
    int tX = blockIdx.x;            // 0..15
    int strip = blockIdx.y;         // 0..31 (8-row strips)
    int b = blockIdx.z;
    int pxi = tX * 16 + (t & 15);
    int pyi = strip * 8 + (t >> 4);
    int tile = (pyi >> 4) * 16 + tX;
    float px = pixc(pxi), py = pixc(pyi);

    const int* mylist = nullptr;
    int nf;
    if (lists) {
        mylist = lists + ((size_t)b * 256 + tile) * LISTSTRIDE;
        nf = counts[b * 256 + tile];
    } else {
        nf = (NFACES + RCHUNK - 1) & ~(RCHUNK - 1);
    }
    nf = __builtin_amdgcn_readfirstlane(nf);
    const float4* rb = rast + (size_t)b * RASTN * 3;

    // prefetch registers: thread t stages faces t and t+128 of each chunk
    float4 a0, a1, a2, c0, c1, c2;
    auto prefetch = [&](int base) {
        int sA = base + t, sB = base + t + 128;
        int fiA = mylist ? mylist[sA] : min(sA, NFACES);
        int fiB = mylist ? mylist[sB] : min(sB, NFACES);
        const float4* pA = rb + (size_t)fiA * 3;
        const float4* pB = rb + (size_t)fiB * 3;
        a0 = pA[0]; a1 = pA[1]; a2 = pA[2];
        c0 = pB[0]; c1 = pB[1]; c2 = pB[2];
    };

    float zc0 = BIGF, zc1 = BIGF, zc2 = BIGF, zc3 = BIGF;
    float w0c0 = 0.0f, w0c1 = 0.0f, w0c2 = 0.0f, w0c3 = 0.0f;
    float w1c0 = 0.0f, w1c1 = 0.0f, w1c2 = 0.0f, w1c3 = 0.0f;
    int fc0 = -1, fc1 = -1, fc2 = -1, fc3 = -1;

    auto evalf = [&](int j, float& zc, float& w0c, float& w1c, int& fcx) {
        float4 r0 = sR0[j], r1 = sR1[j], r2 = sR2[j];
        float dx = __fsub_rn(px, r0.x);
        float dy = __fsub_rn(py, r0.y);
        float w0 = __fmul_rn(__fadd_rn(__fmul_rn(r0.z, dx), __fmul_rn(r0.w, dy)), r1.z);
        float w1 = __fmul_rn(__fadd_rn(__fmul_rn(r1.x, dx), __fmul_rn(r1.y, dy)), r1.z);
        float w2 = __fsub_rn(__fsub_rn(1.0f, w0), w1);
        float d  = __fadd_rn(__fadd_rn(__fmul_rn(w0, r2.x), __fmul_rn(w1, r2.y)),
                             __fmul_rn(w2, r2.z));
        bool ins = (w0 >= 0.0f) & (w1 >= 0.0f) & (w2 >= 0.0f) & (d < zc);
        if (ins) { zc = d; w0c = w0; w1c = w1; fcx = __float_as_int(r2.w); }
    };

    if (nf > 0) {
        prefetch(0);
        for (int base = 0; base < nf; base += RCHUNK) {
            sR0[t] = a0;       sR1[t] = a1;       sR2[t] = a2;
            sR0[t+128] = c0;   sR1[t+128] = c1;   sR2[t+128] = c2;
            __syncthreads();
            if (base + RCHUNK < nf) prefetch(base + RCHUNK);
            #pragma unroll 4
            for (int j = 0; j < RCHUNK; j += 4) {
                evalf(j+0, zc0, w0c0, w1c0, fc0);
                evalf(j+1, zc1, w0c1, w1c1, fc1);
                evalf(j+2, zc2, w0c2, w1c2, fc2);
                evalf(j+3, zc3, w0c3, w1c3, fc3);
            }
            __syncthreads();
        }
    }

    // exact lexicographic (depth, face-index) merge of the 4 chains
    auto merge = [](float& za, float& w0a, float& w1a, int& fa,
                    float zb, float w0b, float w1b, int fb) {
        bool take = (zb < za) || ((zb == za) && (fb < fa));
        if (take) { za = zb; w0a = w0b; w1a = w1b; fa = fb; }
    };
    merge(zc0, w0c0, w1c0, fc0, zc1, w0c1, w1c1, fc1);
    merge(zc2, w0c2, w1c2, fc2, zc3, w0c3, w1c3, fc3);
    merge(zc0, w0c0, w1c0, fc0, zc2, w0c2, w1c2, fc2);

    // flow = w0*g0 + w1*g1 + w2*g2 (or -2 for background)
    float fx, fy;
    if (fc0 >= 0) {
        const float4* fg = flowg + ((size_t)b * NFACES + fc0) * 2;
        float4 g0 = fg[0];
        float4 g1 = fg[1];
        float w2w = __fsub_rn(__fsub_rn(1.0f, w0c0), w1c0);
        fx = __fadd_rn(__fadd_rn(__fmul_rn(w0c0, g0.x), __fmul_rn(w1c0, g0.z)),
                       __fmul_rn(w2w, g1.x));
        fy = __fadd_rn(__fadd_rn(__fmul_rn(w0c0, g0.y), __fmul_rn(w1c0, g0.w)),
                       __fmul_rn(w2w, g1.y));
    } else {
        fx = -2.0f; fy = -2.0f;
    }

    // grid_sample, bilinear, border padding
    float ix = __fmul_rn(__fsub_rn(__fmul_rn(__fadd_rn(fx, 1.0f), 256.0f), 1.0f), 0.5f);
    float iy = __fmul_rn(__fsub_rn(__fmul_rn(__fadd_rn(fy, 1.0f), 256.0f), 1.0f), 0.5f);
    ix = fminf(fmaxf(ix, 0.0f), 255.0f);
    iy = fminf(fmaxf(iy, 0.0f), 255.0f);
    float x0f = floorf(ix), y0f = floorf(iy);
    float wx = __fsub_rn(ix, x0f), wy = __fsub_rn(iy, y0f);
    int x0i = (int)x0f, y0i = (int)y0f;
    int x1i = min(x0i + 1, 255), y1i = min(y0i + 1, 255);
    float omwx = __fsub_rn(1.0f, wx), omwy = __fsub_rn(1.0f, wy);
    float wa = __fmul_rn(omwx, omwy);
    float wb = __fmul_rn(wx, omwy);
    float wc = __fmul_rn(omwx, wy);
    float wd = __fmul_rn(wx, wy);
    const float* img = src_img + (size_t)b * 3 * HH * WW;
    int o00 = y0i * WW + x0i, o01 = y0i * WW + x1i;
    int o10 = y1i * WW + x0i, o11 = y1i * WW + x1i;
    float* ob = out + (size_t)b * 3 * HH * WW + (size_t)pyi * WW + pxi;
    for (int c = 0; c < 3; ++c) {
        const float* ic = img + (size_t)c * HH * WW;
        float Ia = ic[o00], Ib = ic[o01], Ic = ic[o10], Id = ic[o11];
        float val = __fadd_rn(__fadd_rn(__fadd_rn(__fmul_rn(Ia, wa), __fmul_rn(Ib, wb)),
                                        __fmul_rn(Ic, wc)),
                              __fmul_rn(Id, wd));
        ob[(size_t)c * HH * WW] = val;
    }
}

extern "C" void kernel_launch(void* const* d_in, const int* in_sizes, int n_in,
                              void* d_out, int out_size, void* d_ws, size_t ws_size,
                              hipStream_t stream)
{
    const float* src_img   = (const float*)d_in[0];
    const float* src_cam   = (const float*)d_in[1];
    const float* src_verts = (const float*)d_in[2];
    const float* tgt_cam   = (const float*)d_in[3];
    const float* tgt_verts = (const float*)d_in[4];
    const int*   faces     = (const int*)d_in[5];
    int B = in_sizes[1] / 3;   // src_cam is [B,3]

    size_t off = 0;
    auto alloc = [&](size_t bytes) {
        size_t o = off;
        off = (off + bytes + 255) & ~(size_t)255;
        return o;
    };
    size_t rastOff = alloc((size_t)B * RASTN * 3 * sizeof(float4));
    size_t flowOff = alloc((size_t)B * NFACES * 2 * sizeof(float4));
    size_t cntOff  = alloc((size_t)B * 256 * sizeof(int));
    size_t listOff = alloc((size_t)B * 256 * LISTSTRIDE * sizeof(int));
    bool binned = (off <= ws_size);

    char* ws = (char*)d_ws;
    float4* rast  = (float4*)(ws + rastOff);
    float4* flowg = (float4*)(ws + flowOff);
    int* counts = binned ? (int*)(ws + cntOff)  : nullptr;
    int* lists  = binned ? (int*)(ws + listOff) : nullptr;

    int total = B * RASTN;
    precompute_kernel<<<(total + 255) / 256, 256, 0, stream>>>(
        src_cam, src_verts, tgt_cam, tgt_verts, faces, rast, flowg, B);
    if (binned) {
        bin_kernel<<<dim3(256, B), 64, 0, stream>>>(rast, lists, counts, B);
    }
    raster_kernel<<<dim3(16, 32, B), 128, 0, stream>>>(
        rast, flowg, lists, counts, src_img, (float*)d_out, B);
}

// Round 4
// 330.087 us; speedup vs baseline: 3.7292x; 3.7292x over previous
//
#include <hip/hip_runtime.h>

#pragma clang fp contract(off)

#define HH 256
#define WW 256
#define NVERTS 6890
#define NFACES 13776
#define RASTN (NFACES + 1)          // +1 sentinel face (depth=BIG, never wins)
#define LISTSTRIDE 14080            // >= max padded count 13824
#define MAXCHUNKS 54                // ceil(13824/256)
#define BIGF 1000000000.0f
#define EPSF 1e-8f
#define RCHUNK 256

// c(i) = ((i+0.5)/256)*2 - 1  -- exact in f32, matches reference pixel coords
__device__ __forceinline__ float pixc(int i) {
    return __fsub_rn(__fmul_rn(__fdiv_rn(__fadd_rn((float)i, 0.5f), 256.0f), 2.0f), 1.0f);
}

// order-preserving float->uint (all finite values, negatives included)
__device__ __forceinline__ unsigned int fsort(float f) {
    unsigned int u = __float_as_uint(f);
    return (u & 0x80000000u) ? ~u : (u | 0x80000000u);
}

// ---------------------------------------------------------------------------
// Kernel 1: per (b, face) precompute (+ sentinel at f == NFACES).
// rast[idx*3+0] = {x2, y2, A, B} ; [1] = {C, D, inv, 0} ; [2] = {z0,z1,z2,fid}
// Degenerate (|denom|<EPS) and sentinel: depth evaluates to exactly BIG ->
// never wins strict-<, identical to ref's inside &= |denom|>=EPS.
// ---------------------------------------------------------------------------
__global__ __launch_bounds__(256) void precompute_kernel(
    const float* __restrict__ src_cam, const float* __restrict__ src_verts,
    const float* __restrict__ tgt_cam, const float* __restrict__ tgt_verts,
    const int* __restrict__ faces,
    float4* __restrict__ rast, float4* __restrict__ flowg, int B)
{
    int idx = blockIdx.x * blockDim.x + threadIdx.x;
    if (idx >= B * RASTN) return;
    int b = idx / RASTN;
    int f = idx - b * RASTN;
    float4* rr = rast + ((size_t)b * RASTN + f) * 3;
    if (f == NFACES) {   // sentinel
        rr[0] = make_float4(0.0f, 0.0f, 0.0f, 0.0f);
        rr[1] = make_float4(0.0f, 0.0f, 1.0f, 0.0f);
        rr[2] = make_float4(BIGF, BIGF, BIGF, __int_as_float(-1));
        return;
    }
    int i0 = faces[3*f+0], i1 = faces[3*f+1], i2 = faces[3*f+2];

    float tc0 = tgt_cam[3*b+0], tc1 = tgt_cam[3*b+1], tc2 = tgt_cam[3*b+2];
    const float* tv = tgt_verts + (size_t)b * NVERTS * 3;
    float x0 = __fmul_rn(tc0, __fadd_rn(tv[3*i0+0], tc1));
    float y0 = -__fmul_rn(tc0, __fadd_rn(tv[3*i0+1], tc2));
    float z0 = tv[3*i0+2];
    float x1 = __fmul_rn(tc0, __fadd_rn(tv[3*i1+0], tc1));
    float y1 = -__fmul_rn(tc0, __fadd_rn(tv[3*i1+1], tc2));
    float z1 = tv[3*i1+2];
    float x2 = __fmul_rn(tc0, __fadd_rn(tv[3*i2+0], tc1));
    float y2 = -__fmul_rn(tc0, __fadd_rn(tv[3*i2+1], tc2));
    float z2 = tv[3*i2+2];

    float A  = __fsub_rn(y1, y2);
    float D  = __fsub_rn(x0, x2);
    float Bc = __fsub_rn(x2, x1);
    float E  = __fsub_rn(y0, y2);
    float denom = __fadd_rn(__fmul_rn(A, D), __fmul_rn(Bc, E));
    bool valid = (fabsf(denom) >= EPSF);
    float inv = __fdiv_rn(1.0f, valid ? denom : 1.0f);
    float Cc = __fsub_rn(y2, y0);

    if (valid) {
        rr[0] = make_float4(x2, y2, A, Bc);
        rr[1] = make_float4(Cc, D, inv, 0.0f);
        rr[2] = make_float4(z0, z1, z2, __int_as_float(f));
    } else {
        rr[0] = make_float4(0.0f, 0.0f, 0.0f, 0.0f);
        rr[1] = make_float4(0.0f, 0.0f, 1.0f, 0.0f);
        rr[2] = make_float4(BIGF, BIGF, BIGF, __int_as_float(f));
    }

    float sc0 = src_cam[3*b+0], sc1 = src_cam[3*b+1], sc2 = src_cam[3*b+2];
    const float* sv = src_verts + (size_t)b * NVERTS * 3;
    float g0x = __fmul_rn(sc0, __fadd_rn(sv[3*i0+0], sc1));
    float g0y = __fmul_rn(sc0, __fadd_rn(sv[3*i0+1], sc2));
    float g1x = __fmul_rn(sc0, __fadd_rn(sv[3*i1+0], sc1));
    float g1y = __fmul_rn(sc0, __fadd_rn(sv[3*i1+1], sc2));
    float g2x = __fmul_rn(sc0, __fadd_rn(sv[3*i2+0], sc1));
    float g2y = __fmul_rn(sc0, __fadd_rn(sv[3*i2+1], sc2));
    size_t fo = ((size_t)b * NFACES + f) * 2;
    flowg[fo+0] = make_float4(g0x, g0y, g1x, g1y);
    flowg[fo+1] = make_float4(g2x, g2y, 0.0f, 0.0f);
}

// ---------------------------------------------------------------------------
// Kernel 2: per-tile face lists (256 threads / tile, ordered 4-wave
// compaction -> ascending face order). Interval-arithmetic cull with
// 1e-6-relative margins (conservative for slivers). List padded to a
// multiple of RCHUNK with the sentinel face NFACES; counts[] = padded count.
// ---------------------------------------------------------------------------
__global__ __launch_bounds__(256) void bin_kernel(
    const float4* __restrict__ rast, int* __restrict__ lists,
    int* __restrict__ counts, int B)
{
    int tile = blockIdx.x;          // 0..255
    int b = blockIdx.y;
    int tX = tile & 15, tY = tile >> 4;
    float txmin = pixc(tX * 16), txmax = pixc(tX * 16 + 15);
    float tymin = pixc(tY * 16), tymax = pixc(tY * 16 + 15);

    __shared__ int wcnt[4];
    int lane = threadIdx.x & 63;
    int wv = threadIdx.x >> 6;
    const float4* rb = rast + (size_t)b * RASTN * 3;
    int* mylist = lists + ((size_t)b * 256 + tile) * LISTSTRIDE;
    int total = 0;

    for (int base = 0; base < NFACES; base += 256) {
        int f = base + threadIdx.x;
        bool pass = false;
        if (f < NFACES) {
            float4 r0 = rb[(size_t)f*3+0];
            float4 r1 = rb[(size_t)f*3+1];
            float dx0 = txmin - r0.x, dx1 = txmax - r0.x;
            float dy0 = tymin - r0.y, dy1 = tymax - r0.y;
            float mx = fmaxf(fabsf(dx0), fabsf(dx1));
            float my = fmaxf(fabsf(dy0), fabsf(dy1));
            float inv = r1.z, ainv = fabsf(inv);
            float t0max = fmaxf(r0.z*dx0, r0.z*dx1) + fmaxf(r0.w*dy0, r0.w*dy1);
            float t0min = fminf(r0.z*dx0, r0.z*dx1) + fminf(r0.w*dy0, r0.w*dy1);
            float w0max = fmaxf(t0max*inv, t0min*inv);
            float w0min = fminf(t0max*inv, t0min*inv);
            float am0 = fabsf(r0.z)*mx + fabsf(r0.w)*my;
            float M0 = 1e-6f * (am0*ainv + 1.0f + fmaxf(fabsf(w0max), fabsf(w0min)));
            float t1max = fmaxf(r1.x*dx0, r1.x*dx1) + fmaxf(r1.y*dy0, r1.y*dy1);
            float t1min = fminf(r1.x*dx0, r1.x*dx1) + fminf(r1.y*dy0, r1.y*dy1);
            float w1max = fmaxf(t1max*inv, t1min*inv);
            float w1min = fminf(t1max*inv, t1min*inv);
            float am1 = fabsf(r1.x)*mx + fabsf(r1.y)*my;
            float M1 = 1e-6f * (am1*ainv + 1.0f + fmaxf(fabsf(w1max), fabsf(w1min)));
            float M2 = M0 + M1 + 1e-6f * (1.0f + fabsf(w0min) + fabsf(w1min));
            float w2max = 1.0f - w0min - w1min + M2;
            pass = (w0max + M0 >= 0.0f) && (w1max + M1 >= 0.0f) && (w2max >= 0.0f);
        }
        unsigned long long m = __ballot(pass);
        if (lane == 0) wcnt[wv] = __popcll(m);
        __syncthreads();
        int off = total;
        for (int w = 0; w < wv; ++w) off += wcnt[w];
        if (pass) {
            int pre = __popcll(m & ((1ull << lane) - 1ull));
            mylist[off + pre] = f;
        }
        total += wcnt[0] + wcnt[1] + wcnt[2] + wcnt[3];
        __syncthreads();
    }
    int nfp = (total + RCHUNK - 1) & ~(RCHUNK - 1);
    for (int i = total + threadIdx.x; i < nfp; i += 256) mylist[i] = NFACES;
    if (threadIdx.x == 0) counts[b * 256 + tile] = nfp;
}

// ---------------------------------------------------------------------------
// Kernel 3: raster pass. One block per (b, tile, 256-face chunk) -> balanced,
// critical path = 256 faces. 256 threads = 1 pixel each (16x16 tile). Chunk
// staged to SoA LDS (inner reads wave-uniform broadcast). 4 independent
// z-chains in registers, merged lexicographically, then ONE u64 atomicMin
// per pixel: packed (sortable_depth<<32 | fid) == exact lexicographic
// (depth, face index) min == reference's first-argmin + strict-< semantics.
// All depth math `_rn`, no FMA contraction -> bit-identical to reference.
// ---------------------------------------------------------------------------
__global__ __launch_bounds__(256) void raster_kernel(
    const float4* __restrict__ rast,
    const int* __restrict__ lists, const int* __restrict__ counts,
    unsigned long long* __restrict__ zbuf, int B)
{
    int tb = blockIdx.x;
    int b = tb >> 8, tile = tb & 255;
    int chunk = blockIdx.y;
    int nf = lists ? counts[b * 256 + tile] : ((NFACES + RCHUNK - 1) & ~(RCHUNK - 1));
    if (chunk * RCHUNK >= nf) return;

    __shared__ float4 sR0[RCHUNK], sR1[RCHUNK], sR2[RCHUNK];
    int t = threadIdx.x;
    int fi;
    if (lists) fi = lists[((size_t)b * 256 + tile) * LISTSTRIDE + chunk * RCHUNK + t];
    else       fi = min(chunk * RCHUNK + t, NFACES);
    const float4* p = rast + ((size_t)b * RASTN + fi) * 3;
    sR0[t] = p[0]; sR1[t] = p[1]; sR2[t] = p[2];
    __syncthreads();

    int tX = tile & 15, tY = tile >> 4;
    int pxi = tX * 16 + (t & 15);
    int pyi = tY * 16 + (t >> 4);
    float px = pixc(pxi), py = pixc(pyi);

    float zc0 = BIGF, zc1 = BIGF, zc2 = BIGF, zc3 = BIGF;
    int fc0 = -1, fc1 = -1, fc2 = -1, fc3 = -1;

    auto evalf = [&](int j, float& zc, int& fcx) {
        float4 r0 = sR0[j], r1 = sR1[j], r2 = sR2[j];
        float dx = __fsub_rn(px, r0.x);
        float dy = __fsub_rn(py, r0.y);
        float w0 = __fmul_rn(__fadd_rn(__fmul_rn(r0.z, dx), __fmul_rn(r0.w, dy)), r1.z);
        float w1 = __fmul_rn(__fadd_rn(__fmul_rn(r1.x, dx), __fmul_rn(r1.y, dy)), r1.z);
        float w2 = __fsub_rn(__fsub_rn(1.0f, w0), w1);
        float d  = __fadd_rn(__fadd_rn(__fmul_rn(w0, r2.x), __fmul_rn(w1, r2.y)),
                             __fmul_rn(w2, r2.z));
        bool ins = (w0 >= 0.0f) & (w1 >= 0.0f) & (w2 >= 0.0f) & (d < zc);
        if (ins) { zc = d; fcx = __float_as_int(r2.w); }
    };

    #pragma unroll 4
    for (int j = 0; j < RCHUNK; j += 4) {
        evalf(j+0, zc0, fc0);
        evalf(j+1, zc1, fc1);
        evalf(j+2, zc2, fc2);
        evalf(j+3, zc3, fc3);
    }
    // exact lexicographic (depth, face-index) merge of the 4 chains
    auto merge = [](float& za, int& fa, float zb, int fb) {
        bool take = (zb < za) || ((zb == za) && ((unsigned)fb < (unsigned)fa));
        if (take) { za = zb; fa = fb; }
    };
    merge(zc0, fc0, zc1, fc1);
    merge(zc2, fc2, zc3, fc3);
    merge(zc0, fc0, zc2, fc2);

    if (fc0 >= 0) {
        unsigned long long pk = ((unsigned long long)fsort(zc0) << 32) | (unsigned int)fc0;
        atomicMin(&zbuf[((size_t)b << 16) | (pyi << 8) | pxi], pk);
    }
}

// ---------------------------------------------------------------------------
// Kernel 4: resolve. Per pixel: read winning fid, recompute w0,w1 from rast
// (same _rn sequence -> bit-identical), flow gather, bilinear grid sample.
// ---------------------------------------------------------------------------
__global__ __launch_bounds__(256) void resolve_kernel(
    const float4* __restrict__ rast, const float4* __restrict__ flowg,
    const unsigned long long* __restrict__ zbuf,
    const float* __restrict__ src_img, float* __restrict__ out, int B)
{
    int idx = blockIdx.x * 256 + threadIdx.x;
    if (idx >= B * HH * WW) return;
    int b = idx >> 16;
    int pix = idx & 65535;
    int pxi = pix & 255, pyi = pix >> 8;
    float px = pixc(pxi), py = pixc(pyi);

    unsigned int fid = (unsigned int)zbuf[idx];
    float fx, fy;
    if (fid != 0xFFFFFFFFu) {
        const float4* rr = rast + ((size_t)b * RASTN + fid) * 3;
        float4 r0 = rr[0], r1 = rr[1];
        float dx = __fsub_rn(px, r0.x);
        float dy = __fsub_rn(py, r0.y);
        float w0 = __fmul_rn(__fadd_rn(__fmul_rn(r0.z, dx), __fmul_rn(r0.w, dy)), r1.z);
        float w1 = __fmul_rn(__fadd_rn(__fmul_rn(r1.x, dx), __fmul_rn(r1.y, dy)), r1.z);
        float w2 = __fsub_rn(__fsub_rn(1.0f, w0), w1);
        const float4* fg = flowg + ((size_t)b * NFACES + fid) * 2;
        float4 g0 = fg[0];
        float4 g1 = fg[1];
        fx = __fadd_rn(__fadd_rn(__fmul_rn(w0, g0.x), __fmul_rn(w1, g0.z)),
                       __fmul_rn(w2, g1.x));
        fy = __fadd_rn(__fadd_rn(__fmul_rn(w0, g0.y), __fmul_rn(w1, g0.w)),
                       __fmul_rn(w2, g1.y));
    } else {
        fx = -2.0f; fy = -2.0f;
    }

    float ix = __fmul_rn(__fsub_rn(__fmul_rn(__fadd_rn(fx, 1.0f), 256.0f), 1.0f), 0.5f);
    float iy = __fmul_rn(__fsub_rn(__fmul_rn(__fadd_rn(fy, 1.0f), 256.0f), 1.0f), 0.5f);
    ix = fminf(fmaxf(ix, 0.0f), 255.0f);
    iy = fminf(fmaxf(iy, 0.0f), 255.0f);
    float x0f = floorf(ix), y0f = floorf(iy);
    float wx = __fsub_rn(ix, x0f), wy = __fsub_rn(iy, y0f);
    int x0i = (int)x0f, y0i = (int)y0f;
    int x1i = min(x0i + 1, 255), y1i = min(y0i + 1, 255);
    float omwx = __fsub_rn(1.0f, wx), omwy = __fsub_rn(1.0f, wy);
    float wa = __fmul_rn(omwx, omwy);
    float wb = __fmul_rn(wx, omwy);
    float wc = __fmul_rn(omwx, wy);
    float wd = __fmul_rn(wx, wy);
    const float* img = src_img + (size_t)b * 3 * HH * WW;
    int o00 = y0i * WW + x0i, o01 = y0i * WW + x1i;
    int o10 = y1i * WW + x0i, o11 = y1i * WW + x1i;
    float* ob = out + (size_t)b * 3 * HH * WW + (size_t)pyi * WW + pxi;
    for (int c = 0; c < 3; ++c) {
        const float* ic = img + (size_t)c * HH * WW;
        float Ia = ic[o00], Ib = ic[o01], Ic = ic[o10], Id = ic[o11];
        float val = __fadd_rn(__fadd_rn(__fadd_rn(__fmul_rn(Ia, wa), __fmul_rn(Ib, wb)),
                                        __fmul_rn(Ic, wc)),
                              __fmul_rn(Id, wd));
        ob[(size_t)c * HH * WW] = val;
    }
}

extern "C" void kernel_launch(void* const* d_in, const int* in_sizes, int n_in,
                              void* d_out, int out_size, void* d_ws, size_t ws_size,
                              hipStream_t stream)
{
    const float* src_img   = (const float*)d_in[0];
    const float* src_cam   = (const float*)d_in[1];
    const float* src_verts = (const float*)d_in[2];
    const float* tgt_cam   = (const float*)d_in[3];
    const float* tgt_verts = (const float*)d_in[4];
    const int*   faces     = (const int*)d_in[5];
    int B = in_sizes[1] / 3;   // src_cam is [B,3]

    size_t off = 0;
    auto alloc = [&](size_t bytes) {
        size_t o = off;
        off = (off + bytes + 255) & ~(size_t)255;
        return o;
    };
    size_t rastOff = alloc((size_t)B * RASTN * 3 * sizeof(float4));
    size_t flowOff = alloc((size_t)B * NFACES * 2 * sizeof(float4));
    size_t zbufOff = alloc((size_t)B * HH * WW * sizeof(unsigned long long));
    size_t cntOff  = alloc((size_t)B * 256 * sizeof(int));
    size_t listOff = alloc((size_t)B * 256 * LISTSTRIDE * sizeof(int));
    bool binned = (off <= ws_size);

    char* ws = (char*)d_ws;
    float4* rast  = (float4*)(ws + rastOff);
    float4* flowg = (float4*)(ws + flowOff);
    unsigned long long* zbuf = (unsigned long long*)(ws + zbufOff);
    int* counts = binned ? (int*)(ws + cntOff)  : nullptr;
    int* lists  = binned ? (int*)(ws + listOff) : nullptr;

    // zbuf init to max u64 (background sentinel)
    hipMemsetAsync(zbuf, 0xFF, (size_t)B * HH * WW * sizeof(unsigned long long), stream);

    int total = B * RASTN;
    precompute_kernel<<<(total + 255) / 256, 256, 0, stream>>>(
        src_cam, src_verts, tgt_cam, tgt_verts, faces, rast, flowg, B);
    if (binned) {
        bin_kernel<<<dim3(256, B), 256, 0, stream>>>(rast, lists, counts, B);
    }
    raster_kernel<<<dim3(B * 256, MAXCHUNKS), 256, 0, stream>>>(
        rast, lists, counts, zbuf, B);
    resolve_kernel<<<(B * HH * WW + 255) / 256, 256, 0, stream>>>(
        rast, flowg, zbuf, src_img, (float*)d_out, B);
}

// Round 5
// 274.449 us; speedup vs baseline: 4.4852x; 1.2027x over previous
//
#include <hip/hip_runtime.h>

#pragma clang fp contract(off)

#define HH 256
#define WW 256
#define NVERTS 6890
#define NFACES 13776
#define RASTN (NFACES + 1)          // +1 sentinel face (depth=BIG, never wins)
#define LISTSTRIDE 14080            // >= max padded count 13824
#define RCHUNK 128
#define MAXCHUNKS 108               // 13824 / 128
#define BIGF 1000000000.0f
#define EPSF 1e-8f

// c(i) = ((i+0.5)/256)*2 - 1  -- exact in f32, matches reference pixel coords
__device__ __forceinline__ float pixc(int i) {
    return __fsub_rn(__fmul_rn(__fdiv_rn(__fadd_rn((float)i, 0.5f), 256.0f), 2.0f), 1.0f);
}

// order-preserving float->uint (all finite values, negatives included)
__device__ __forceinline__ unsigned int fsort(float f) {
    unsigned int u = __float_as_uint(f);
    return (u & 0x80000000u) ? ~u : (u | 0x80000000u);
}

// ---------------------------------------------------------------------------
// Kernel 1: per (b, face) precompute (+ sentinel at f == NFACES).
// rast[idx*3+0] = {x2, y2, A, B} ; [1] = {C, D, inv, 0} ; [2] = {z0,z1,z2,fid}
// Degenerate (|denom|<EPS) and sentinel: depth evaluates to exactly BIG ->
// never wins strict-<, identical to ref's inside &= |denom|>=EPS.
// ---------------------------------------------------------------------------
__global__ __launch_bounds__(256) void precompute_kernel(
    const float* __restrict__ src_cam, const float* __restrict__ src_verts,
    const float* __restrict__ tgt_cam, const float* __restrict__ tgt_verts,
    const int* __restrict__ faces,
    float4* __restrict__ rast, float4* __restrict__ flowg, int B)
{
    int idx = blockIdx.x * blockDim.x + threadIdx.x;
    if (idx >= B * RASTN) return;
    int b = idx / RASTN;
    int f = idx - b * RASTN;
    float4* rr = rast + ((size_t)b * RASTN + f) * 3;
    if (f == NFACES) {   // sentinel
        rr[0] = make_float4(0.0f, 0.0f, 0.0f, 0.0f);
        rr[1] = make_float4(0.0f, 0.0f, 1.0f, 0.0f);
        rr[2] = make_float4(BIGF, BIGF, BIGF, __int_as_float(-1));
        return;
    }
    int i0 = faces[3*f+0], i1 = faces[3*f+1], i2 = faces[3*f+2];

    float tc0 = tgt_cam[3*b+0], tc1 = tgt_cam[3*b+1], tc2 = tgt_cam[3*b+2];
    const float* tv = tgt_verts + (size_t)b * NVERTS * 3;
    float x0 = __fmul_rn(tc0, __fadd_rn(tv[3*i0+0], tc1));
    float y0 = -__fmul_rn(tc0, __fadd_rn(tv[3*i0+1], tc2));
    float z0 = tv[3*i0+2];
    float x1 = __fmul_rn(tc0, __fadd_rn(tv[3*i1+0], tc1));
    float y1 = -__fmul_rn(tc0, __fadd_rn(tv[3*i1+1], tc2));
    float z1 = tv[3*i1+2];
    float x2 = __fmul_rn(tc0, __fadd_rn(tv[3*i2+0], tc1));
    float y2 = -__fmul_rn(tc0, __fadd_rn(tv[3*i2+1], tc2));
    float z2 = tv[3*i2+2];

    float A  = __fsub_rn(y1, y2);
    float D  = __fsub_rn(x0, x2);
    float Bc = __fsub_rn(x2, x1);
    float E  = __fsub_rn(y0, y2);
    float denom = __fadd_rn(__fmul_rn(A, D), __fmul_rn(Bc, E));
    bool valid = (fabsf(denom) >= EPSF);
    float inv = __fdiv_rn(1.0f, valid ? denom : 1.0f);
    float Cc = __fsub_rn(y2, y0);

    if (valid) {
        rr[0] = make_float4(x2, y2, A, Bc);
        rr[1] = make_float4(Cc, D, inv, 0.0f);
        rr[2] = make_float4(z0, z1, z2, __int_as_float(f));
    } else {
        rr[0] = make_float4(0.0f, 0.0f, 0.0f, 0.0f);
        rr[1] = make_float4(0.0f, 0.0f, 1.0f, 0.0f);
        rr[2] = make_float4(BIGF, BIGF, BIGF, __int_as_float(f));
    }

    float sc0 = src_cam[3*b+0], sc1 = src_cam[3*b+1], sc2 = src_cam[3*b+2];
    const float* sv = src_verts + (size_t)b * NVERTS * 3;
    float g0x = __fmul_rn(sc0, __fadd_rn(sv[3*i0+0], sc1));
    float g0y = __fmul_rn(sc0, __fadd_rn(sv[3*i0+1], sc2));
    float g1x = __fmul_rn(sc0, __fadd_rn(sv[3*i1+0], sc1));
    float g1y = __fmul_rn(sc0, __fadd_rn(sv[3*i1+1], sc2));
    float g2x = __fmul_rn(sc0, __fadd_rn(sv[3*i2+0], sc1));
    float g2y = __fmul_rn(sc0, __fadd_rn(sv[3*i2+1], sc2));
    size_t fo = ((size_t)b * NFACES + f) * 2;
    flowg[fo+0] = make_float4(g0x, g0y, g1x, g1y);
    flowg[fo+1] = make_float4(g2x, g2y, 0.0f, 0.0f);
}

// ---------------------------------------------------------------------------
// Kernel 2: per-tile face lists (256 threads / tile, ordered 4-wave
// compaction -> ascending face order). Interval-arithmetic cull with
// 1e-6-relative margins (conservative for slivers). List padded to a
// multiple of RCHUNK with the sentinel face NFACES; counts[] = padded count.
// ---------------------------------------------------------------------------
__global__ __launch_bounds__(256) void bin_kernel(
    const float4* __restrict__ rast, int* __restrict__ lists,
    int* __restrict__ counts, int B)
{
    int tile = blockIdx.x;          // 0..255
    int b = blockIdx.y;
    int tX = tile & 15, tY = tile >> 4;
    float txmin = pixc(tX * 16), txmax = pixc(tX * 16 + 15);
    float tymin = pixc(tY * 16), tymax = pixc(tY * 16 + 15);

    __shared__ int wcnt[4];
    int lane = threadIdx.x & 63;
    int wv = threadIdx.x >> 6;
    const float4* rb = rast + (size_t)b * RASTN * 3;
    int* mylist = lists + ((size_t)b * 256 + tile) * LISTSTRIDE;
    int total = 0;

    for (int base = 0; base < NFACES; base += 256) {
        int f = base + threadIdx.x;
        bool pass = false;
        if (f < NFACES) {
            float4 r0 = rb[(size_t)f*3+0];
            float4 r1 = rb[(size_t)f*3+1];
            float dx0 = txmin - r0.x, dx1 = txmax - r0.x;
            float dy0 = tymin - r0.y, dy1 = tymax - r0.y;
            float mx = fmaxf(fabsf(dx0), fabsf(dx1));
            float my = fmaxf(fabsf(dy0), fabsf(dy1));
            float inv = r1.z, ainv = fabsf(inv);
            float t0max = fmaxf(r0.z*dx0, r0.z*dx1) + fmaxf(r0.w*dy0, r0.w*dy1);
            float t0min = fminf(r0.z*dx0, r0.z*dx1) + fminf(r0.w*dy0, r0.w*dy1);
            float w0max = fmaxf(t0max*inv, t0min*inv);
            float w0min = fminf(t0max*inv, t0min*inv);
            float am0 = fabsf(r0.z)*mx + fabsf(r0.w)*my;
            float M0 = 1e-6f * (am0*ainv + 1.0f + fmaxf(fabsf(w0max), fabsf(w0min)));
            float t1max = fmaxf(r1.x*dx0, r1.x*dx1) + fmaxf(r1.y*dy0, r1.y*dy1);
            float t1min = fminf(r1.x*dx0, r1.x*dx1) + fminf(r1.y*dy0, r1.y*dy1);
            float w1max = fmaxf(t1max*inv, t1min*inv);
            float w1min = fminf(t1max*inv, t1min*inv);
            float am1 = fabsf(r1.x)*mx + fabsf(r1.y)*my;
            float M1 = 1e-6f * (am1*ainv + 1.0f + fmaxf(fabsf(w1max), fabsf(w1min)));
            float M2 = M0 + M1 + 1e-6f * (1.0f + fabsf(w0min) + fabsf(w1min));
            float w2max = 1.0f - w0min - w1min + M2;
            pass = (w0max + M0 >= 0.0f) && (w1max + M1 >= 0.0f) && (w2max >= 0.0f);
        }
        unsigned long long m = __ballot(pass);
        if (lane == 0) wcnt[wv] = __popcll(m);
        __syncthreads();
        int off = total;
        for (int w = 0; w < wv; ++w) off += wcnt[w];
        if (pass) {
            int pre = __popcll(m & ((1ull << lane) - 1ull));
            mylist[off + pre] = f;
        }
        total += wcnt[0] + wcnt[1] + wcnt[2] + wcnt[3];
        __syncthreads();
    }
    int nfp = (total + RCHUNK - 1) & ~(RCHUNK - 1);
    for (int i = total + threadIdx.x; i < nfp; i += 256) mylist[i] = NFACES;
    if (threadIdx.x == 0) counts[b * 256 + tile] = nfp;
}

// ---------------------------------------------------------------------------
// Kernel 3: raster. One block (64 threads = 1 wave) per (b, tile, 128-face
// chunk). Each lane owns 4 pixels of the 16x16 tile sharing one COLUMN
// (rows r, r+4, r+8, r+12): dx, A*dx, C*dx computed once per face and
// reused bit-identically. 4 independent per-pixel z-chains give ILP.
// LDS: 3 wave-uniform b128 broadcasts per face amortized over 256 px-evals
// (VALU:LDS ~ 13:1 -> issue-bound, vs 4:1 in the previous version).
// One u64 atomicMin per pixel per chunk packs (sortable_depth, fid) ==
// exact lexicographic (depth, face index) min == reference semantics.
// ---------------------------------------------------------------------------
__global__ __launch_bounds__(64) void raster_kernel(
    const float4* __restrict__ rast,
    const int* __restrict__ lists, const int* __restrict__ counts,
    unsigned long long* __restrict__ zbuf, int B)
{
    int tb = blockIdx.x;
    int b = tb >> 8, tile = tb & 255;
    int chunk = blockIdx.y;
    int nf = lists ? counts[b * 256 + tile] : ((NFACES + RCHUNK - 1) & ~(RCHUNK - 1));
    if (chunk * RCHUNK >= nf) return;

    __shared__ float4 sR0[RCHUNK], sR1[RCHUNK], sR2[RCHUNK];
    int t = threadIdx.x;
    // stage 128 faces: threads load faces t and t+64
    const int* lbase = lists ? (lists + ((size_t)b * 256 + tile) * LISTSTRIDE + chunk * RCHUNK)
                             : nullptr;
    #pragma unroll
    for (int s = 0; s < RCHUNK; s += 64) {
        int fi = lbase ? lbase[s + t] : min(chunk * RCHUNK + s + t, NFACES);
        const float4* p = rast + ((size_t)b * RASTN + fi) * 3;
        sR0[s + t] = p[0]; sR1[s + t] = p[1]; sR2[s + t] = p[2];
    }
    __syncthreads();

    int tX = tile & 15, tY = tile >> 4;
    int col = t & 15, row0 = t >> 4;            // lane -> column, base row
    int pxi = tX * 16 + col;
    float px = pixc(pxi);
    float py0 = pixc(tY * 16 + row0);
    float py1 = pixc(tY * 16 + row0 + 4);
    float py2 = pixc(tY * 16 + row0 + 8);
    float py3 = pixc(tY * 16 + row0 + 12);

    float z0c = BIGF, z1c = BIGF, z2c = BIGF, z3c = BIGF;
    int j0c = -1, j1c = -1, j2c = -1, j3c = -1;

    #pragma unroll 4
    for (int j = 0; j < RCHUNK; ++j) {
        float4 r0 = sR0[j], r1 = sR1[j], r2 = sR2[j];
        float dx  = __fsub_rn(px, r0.x);
        float Adx = __fmul_rn(r0.z, dx);        // A*dx, shared by 4 pixels
        float Cdx = __fmul_rn(r1.x, dx);        // C*dx
        auto evalp = [&](float py, float& zc, int& jc) {
            float dy = __fsub_rn(py, r0.y);
            float w0 = __fmul_rn(__fadd_rn(Adx, __fmul_rn(r0.w, dy)), r1.z);
            float w1 = __fmul_rn(__fadd_rn(Cdx, __fmul_rn(r1.y, dy)), r1.z);
            float w2 = __fsub_rn(__fsub_rn(1.0f, w0), w1);
            float d  = __fadd_rn(__fadd_rn(__fmul_rn(w0, r2.x), __fmul_rn(w1, r2.y)),
                                 __fmul_rn(w2, r2.z));
            float m  = fminf(fminf(w0, w1), w2);   // v_min3
            bool ins = (m >= 0.0f) & (d < zc);
            if (ins) { zc = d; jc = j; }
        };
        evalp(py0, z0c, j0c);
        evalp(py1, z1c, j1c);
        evalp(py2, z2c, j2c);
        evalp(py3, z3c, j3c);
    }

    auto commit = [&](int rowk, float zc, int jc) {
        if (jc >= 0) {
            int fid = __float_as_int(sR2[jc].w);
            if (fid >= 0) {
                unsigned long long pk =
                    ((unsigned long long)fsort(zc) << 32) | (unsigned int)fid;
                int pyi = tY * 16 + row0 + rowk * 4;
                atomicMin(&zbuf[((size_t)b << 16) | (pyi << 8) | pxi], pk);
            }
        }
    };
    commit(0, z0c, j0c);
    commit(1, z1c, j1c);
    commit(2, z2c, j2c);
    commit(3, z3c, j3c);
}

// ---------------------------------------------------------------------------
// Kernel 4: resolve. Per pixel: read winning fid, recompute w0,w1 from rast
// (same _rn sequence -> bit-identical), flow gather, bilinear grid sample.
// ---------------------------------------------------------------------------
__global__ __launch_bounds__(256) void resolve_kernel(
    const float4* __restrict__ rast, const float4* __restrict__ flowg,
    const unsigned long long* __restrict__ zbuf,
    const float* __restrict__ src_img, float* __restrict__ out, int B)
{
    int idx = blockIdx.x * 256 + threadIdx.x;
    if (idx >= B * HH * WW) return;
    int b = idx >> 16;
    int pix = idx & 65535;
    int pxi = pix & 255, pyi = pix >> 8;
    float px = pixc(pxi), py = pixc(pyi);

    unsigned int fid = (unsigned int)zbuf[idx];
    float fx, fy;
    if (fid != 0xFFFFFFFFu) {
        const float4* rr = rast + ((size_t)b * RASTN + fid) * 3;
        float4 r0 = rr[0], r1 = rr[1];
        float dx = __fsub_rn(px, r0.x);
        float dy = __fsub_rn(py, r0.y);
        float w0 = __fmul_rn(__fadd_rn(__fmul_rn(r0.z, dx), __fmul_rn(r0.w, dy)), r1.z);
        float w1 = __fmul_rn(__fadd_rn(__fmul_rn(r1.x, dx), __fmul_rn(r1.y, dy)), r1.z);
        float w2 = __fsub_rn(__fsub_rn(1.0f, w0), w1);
        const float4* fg = flowg + ((size_t)b * NFACES + fid) * 2;
        float4 g0 = fg[0];
        float4 g1 = fg[1];
        fx = __fadd_rn(__fadd_rn(__fmul_rn(w0, g0.x), __fmul_rn(w1, g0.z)),
                       __fmul_rn(w2, g1.x));
        fy = __fadd_rn(__fadd_rn(__fmul_rn(w0, g0.y), __fmul_rn(w1, g0.w)),
                       __fmul_rn(w2, g1.y));
    } else {
        fx = -2.0f; fy = -2.0f;
    }

    float ix = __fmul_rn(__fsub_rn(__fmul_rn(__fadd_rn(fx, 1.0f), 256.0f), 1.0f), 0.5f);
    float iy = __fmul_rn(__fsub_rn(__fmul_rn(__fadd_rn(fy, 1.0f), 256.0f), 1.0f), 0.5f);
    ix = fminf(fmaxf(ix, 0.0f), 255.0f);
    iy = fminf(fmaxf(iy, 0.0f), 255.0f);
    float x0f = floorf(ix), y0f = floorf(iy);
    float wx = __fsub_rn(ix, x0f), wy = __fsub_rn(iy, y0f);
    int x0i = (int)x0f, y0i = (int)y0f;
    int x1i = min(x0i + 1, 255), y1i = min(y0i + 1, 255);
    float omwx = __fsub_rn(1.0f, wx), omwy = __fsub_rn(1.0f, wy);
    float wa = __fmul_rn(omwx, omwy);
    float wb = __fmul_rn(wx, omwy);
    float wc = __fmul_rn(omwx, wy);
    float wd = __fmul_rn(wx, wy);
    const float* img = src_img + (size_t)b * 3 * HH * WW;
    int o00 = y0i * WW + x0i, o01 = y0i * WW + x1i;
    int o10 = y1i * WW + x0i, o11 = y1i * WW + x1i;
    float* ob = out + (size_t)b * 3 * HH * WW + (size_t)pyi * WW + pxi;
    for (int c = 0; c < 3; ++c) {
        const float* ic = img + (size_t)c * HH * WW;
        float Ia = ic[o00], Ib = ic[o01], Ic = ic[o10], Id = ic[o11];
        float val = __fadd_rn(__fadd_rn(__fadd_rn(__fmul_rn(Ia, wa), __fmul_rn(Ib, wb)),
                                        __fmul_rn(Ic, wc)),
                              __fmul_rn(Id, wd));
        ob[(size_t)c * HH * WW] = val;
    }
}

extern "C" void kernel_launch(void* const* d_in, const int* in_sizes, int n_in,
                              void* d_out, int out_size, void* d_ws, size_t ws_size,
                              hipStream_t stream)
{
    const float* src_img   = (const float*)d_in[0];
    const float* src_cam   = (const float*)d_in[1];
    const float* src_verts = (const float*)d_in[2];
    const float* tgt_cam   = (const float*)d_in[3];
    const float* tgt_verts = (const float*)d_in[4];
    const int*   faces     = (const int*)d_in[5];
    int B = in_sizes[1] / 3;   // src_cam is [B,3]

    size_t off = 0;
    auto alloc = [&](size_t bytes) {
        size_t o = off;
        off = (off + bytes + 255) & ~(size_t)255;
        return o;
    };
    size_t rastOff = alloc((size_t)B * RASTN * 3 * sizeof(float4));
    size_t flowOff = alloc((size_t)B * NFACES * 2 * sizeof(float4));
    size_t zbufOff = alloc((size_t)B * HH * WW * sizeof(unsigned long long));
    size_t cntOff  = alloc((size_t)B * 256 * sizeof(int));
    size_t listOff = alloc((size_t)B * 256 * LISTSTRIDE * sizeof(int));
    bool binned = (off <= ws_size);

    char* ws = (char*)d_ws;
    float4* rast  = (float4*)(ws + rastOff);
    float4* flowg = (float4*)(ws + flowOff);
    unsigned long long* zbuf = (unsigned long long*)(ws + zbufOff);
    int* counts = binned ? (int*)(ws + cntOff)  : nullptr;
    int* lists  = binned ? (int*)(ws + listOff) : nullptr;

    // zbuf init to max u64 (background sentinel)
    hipMemsetAsync(zbuf, 0xFF, (size_t)B * HH * WW * sizeof(unsigned long long), stream);

    int total = B * RASTN;
    precompute_kernel<<<(total + 255) / 256, 256, 0, stream>>>(
        src_cam, src_verts, tgt_cam, tgt_verts, faces, rast, flowg, B);
    if (binned) {
        bin_kernel<<<dim3(256, B), 256, 0, stream>>>(rast, lists, counts, B);
    }
    raster_kernel<<<dim3(B * 256, MAXCHUNKS), 64, 0, stream>>>(
        rast, lists, counts, zbuf, B);
    resolve_kernel<<<(B * HH * WW + 255) / 256, 256, 0, stream>>>(
        rast, flowg, zbuf, src_img, (float*)d_out, B);
}

// Round 6
// 271.673 us; speedup vs baseline: 4.5310x; 1.0102x over previous
//
#include <hip/hip_runtime.h>

#pragma clang fp contract(off)

#define HH 256
#define WW 256
#define NVERTS 6890
#define NFACES 13776
#define RASTN (NFACES + 1)          // +1 sentinel face (depth=BIG, never wins)
#define LISTSTRIDE 14080            // >= max padded count 13824
#define RCHUNK 128                  // faces per wave
#define GCHUNK 512                  // faces per block (4 waves x 128)
#define MAXGROUPS 27                // ceil(13824/512)
#define BIGF 1000000000.0f
#define EPSF 1e-8f

// c(i) = ((i+0.5)/256)*2 - 1  -- exact in f32, matches reference pixel coords
__device__ __forceinline__ float pixc(int i) {
    return __fsub_rn(__fmul_rn(__fdiv_rn(__fadd_rn((float)i, 0.5f), 256.0f), 2.0f), 1.0f);
}

// order-preserving float->uint (all finite values, negatives included)
__device__ __forceinline__ unsigned int fsort(float f) {
    unsigned int u = __float_as_uint(f);
    return (u & 0x80000000u) ? ~u : (u | 0x80000000u);
}

// ---------------------------------------------------------------------------
// Kernel 1: per (b, face) precompute (+ sentinel at f == NFACES) AND zbuf
// init (grid-stride role sharing -> no separate memset launch).
// rast[idx*3+0] = {x2, y2, A, B} ; [1] = {C, D, inv, 0} ; [2] = {z0,z1,z2,fid}
// Degenerate (|denom|<EPS) and sentinel: depth evaluates to exactly BIG ->
// never wins strict-<, identical to ref's inside &= |denom|>=EPS.
// ---------------------------------------------------------------------------
__global__ __launch_bounds__(256) void precompute_kernel(
    const float* __restrict__ src_cam, const float* __restrict__ src_verts,
    const float* __restrict__ tgt_cam, const float* __restrict__ tgt_verts,
    const int* __restrict__ faces,
    float4* __restrict__ rast, float4* __restrict__ flowg,
    unsigned long long* __restrict__ zbuf, int B)
{
    int idx = blockIdx.x * blockDim.x + threadIdx.x;
    if (idx < B * HH * WW) zbuf[idx] = ~0ull;   // background sentinel
    if (idx >= B * RASTN) return;
    int b = idx / RASTN;
    int f = idx - b * RASTN;
    float4* rr = rast + ((size_t)b * RASTN + f) * 3;
    if (f == NFACES) {   // sentinel face
        rr[0] = make_float4(0.0f, 0.0f, 0.0f, 0.0f);
        rr[1] = make_float4(0.0f, 0.0f, 1.0f, 0.0f);
        rr[2] = make_float4(BIGF, BIGF, BIGF, __int_as_float(-1));
        return;
    }
    int i0 = faces[3*f+0], i1 = faces[3*f+1], i2 = faces[3*f+2];

    float tc0 = tgt_cam[3*b+0], tc1 = tgt_cam[3*b+1], tc2 = tgt_cam[3*b+2];
    const float* tv = tgt_verts + (size_t)b * NVERTS * 3;
    float x0 = __fmul_rn(tc0, __fadd_rn(tv[3*i0+0], tc1));
    float y0 = -__fmul_rn(tc0, __fadd_rn(tv[3*i0+1], tc2));
    float z0 = tv[3*i0+2];
    float x1 = __fmul_rn(tc0, __fadd_rn(tv[3*i1+0], tc1));
    float y1 = -__fmul_rn(tc0, __fadd_rn(tv[3*i1+1], tc2));
    float z1 = tv[3*i1+2];
    float x2 = __fmul_rn(tc0, __fadd_rn(tv[3*i2+0], tc1));
    float y2 = -__fmul_rn(tc0, __fadd_rn(tv[3*i2+1], tc2));
    float z2 = tv[3*i2+2];

    float A  = __fsub_rn(y1, y2);
    float D  = __fsub_rn(x0, x2);
    float Bc = __fsub_rn(x2, x1);
    float E  = __fsub_rn(y0, y2);
    float denom = __fadd_rn(__fmul_rn(A, D), __fmul_rn(Bc, E));
    bool valid = (fabsf(denom) >= EPSF);
    float inv = __fdiv_rn(1.0f, valid ? denom : 1.0f);
    float Cc = __fsub_rn(y2, y0);

    if (valid) {
        rr[0] = make_float4(x2, y2, A, Bc);
        rr[1] = make_float4(Cc, D, inv, 0.0f);
        rr[2] = make_float4(z0, z1, z2, __int_as_float(f));
    } else {
        rr[0] = make_float4(0.0f, 0.0f, 0.0f, 0.0f);
        rr[1] = make_float4(0.0f, 0.0f, 1.0f, 0.0f);
        rr[2] = make_float4(BIGF, BIGF, BIGF, __int_as_float(f));
    }

    float sc0 = src_cam[3*b+0], sc1 = src_cam[3*b+1], sc2 = src_cam[3*b+2];
    const float* sv = src_verts + (size_t)b * NVERTS * 3;
    float g0x = __fmul_rn(sc0, __fadd_rn(sv[3*i0+0], sc1));
    float g0y = __fmul_rn(sc0, __fadd_rn(sv[3*i0+1], sc2));
    float g1x = __fmul_rn(sc0, __fadd_rn(sv[3*i1+0], sc1));
    float g1y = __fmul_rn(sc0, __fadd_rn(sv[3*i1+1], sc2));
    float g2x = __fmul_rn(sc0, __fadd_rn(sv[3*i2+0], sc1));
    float g2y = __fmul_rn(sc0, __fadd_rn(sv[3*i2+1], sc2));
    size_t fo = ((size_t)b * NFACES + f) * 2;
    flowg[fo+0] = make_float4(g0x, g0y, g1x, g1y);
    flowg[fo+1] = make_float4(g2x, g2y, 0.0f, 0.0f);
}

// ---------------------------------------------------------------------------
// Kernel 2: per-tile face lists (256 threads / tile, ordered 4-wave
// compaction -> ascending face order). Interval-arithmetic cull with
// 1e-6-relative margins (conservative for slivers). List padded to a
// multiple of RCHUNK with the sentinel face NFACES; counts[] = padded count.
// ---------------------------------------------------------------------------
__global__ __launch_bounds__(256) void bin_kernel(
    const float4* __restrict__ rast, int* __restrict__ lists,
    int* __restrict__ counts, int B)
{
    int tile = blockIdx.x;          // 0..255
    int b = blockIdx.y;
    int tX = tile & 15, tY = tile >> 4;
    float txmin = pixc(tX * 16), txmax = pixc(tX * 16 + 15);
    float tymin = pixc(tY * 16), tymax = pixc(tY * 16 + 15);

    __shared__ int wcnt[4];
    int lane = threadIdx.x & 63;
    int wv = threadIdx.x >> 6;
    const float4* rb = rast + (size_t)b * RASTN * 3;
    int* mylist = lists + ((size_t)b * 256 + tile) * LISTSTRIDE;
    int total = 0;

    for (int base = 0; base < NFACES; base += 256) {
        int f = base + threadIdx.x;
        bool pass = false;
        if (f < NFACES) {
            float4 r0 = rb[(size_t)f*3+0];
            float4 r1 = rb[(size_t)f*3+1];
            float dx0 = txmin - r0.x, dx1 = txmax - r0.x;
            float dy0 = tymin - r0.y, dy1 = tymax - r0.y;
            float mx = fmaxf(fabsf(dx0), fabsf(dx1));
            float my = fmaxf(fabsf(dy0), fabsf(dy1));
            float inv = r1.z, ainv = fabsf(inv);
            float t0max = fmaxf(r0.z*dx0, r0.z*dx1) + fmaxf(r0.w*dy0, r0.w*dy1);
            float t0min = fminf(r0.z*dx0, r0.z*dx1) + fminf(r0.w*dy0, r0.w*dy1);
            float w0max = fmaxf(t0max*inv, t0min*inv);
            float w0min = fminf(t0max*inv, t0min*inv);
            float am0 = fabsf(r0.z)*mx + fabsf(r0.w)*my;
            float M0 = 1e-6f * (am0*ainv + 1.0f + fmaxf(fabsf(w0max), fabsf(w0min)));
            float t1max = fmaxf(r1.x*dx0, r1.x*dx1) + fmaxf(r1.y*dy0, r1.y*dy1);
            float t1min = fminf(r1.x*dx0, r1.x*dx1) + fminf(r1.y*dy0, r1.y*dy1);
            float w1max = fmaxf(t1max*inv, t1min*inv);
            float w1min = fminf(t1max*inv, t1min*inv);
            float am1 = fabsf(r1.x)*mx + fabsf(r1.y)*my;
            float M1 = 1e-6f * (am1*ainv + 1.0f + fmaxf(fabsf(w1max), fabsf(w1min)));
            float M2 = M0 + M1 + 1e-6f * (1.0f + fabsf(w0min) + fabsf(w1min));
            float w2max = 1.0f - w0min - w1min + M2;
            pass = (w0max + M0 >= 0.0f) && (w1max + M1 >= 0.0f) && (w2max >= 0.0f);
        }
        unsigned long long m = __ballot(pass);
        if (lane == 0) wcnt[wv] = __popcll(m);
        __syncthreads();
        int off = total;
        for (int w = 0; w < wv; ++w) off += wcnt[w];
        if (pass) {
            int pre = __popcll(m & ((1ull << lane) - 1ull));
            mylist[off + pre] = f;
        }
        total += wcnt[0] + wcnt[1] + wcnt[2] + wcnt[3];
        __syncthreads();
    }
    int nfp = (total + RCHUNK - 1) & ~(RCHUNK - 1);
    for (int i = total + threadIdx.x; i < nfp; i += 256) mylist[i] = NFACES;
    if (threadIdx.x == 0) counts[b * 256 + tile] = nfp;
}

// ---------------------------------------------------------------------------
// Kernel 3: raster. One block (256 threads = 4 waves) per (b, tile, group of
// 512 faces). Block stages 512 faces to LDS (24.6 KB -> 6 WGs = 24 waves/CU
// resident); wave w scans its own 128-face chunk over the FULL 16x16 tile.
// Each lane owns 4 pixels sharing one column: dx, A*dx, C*dx computed once
// per face (bit-identical reuse). Staging guards pos<nf with the sentinel
// face. One u64 atomicMin per pixel per chunk packs (sortable_depth, fid)
// == exact lexicographic (depth, face index) min == reference's
// first-argmin + strict-< semantics. All depth math _rn, no contraction.
// ---------------------------------------------------------------------------
__global__ __launch_bounds__(256) void raster_kernel(
    const float4* __restrict__ rast,
    const int* __restrict__ lists, const int* __restrict__ counts,
    unsigned long long* __restrict__ zbuf, int B)
{
    int tb = blockIdx.x;
    int b = tb >> 8, tile = tb & 255;
    int group = blockIdx.y;
    int nf = lists ? counts[b * 256 + tile] : NFACES;
    int gbase = group * GCHUNK;
    if (gbase >= nf) return;

    __shared__ float4 sR0[GCHUNK], sR1[GCHUNK], sR2[GCHUNK];
    int t = threadIdx.x;
    const int* lbase = lists ? (lists + ((size_t)b * 256 + tile) * LISTSTRIDE) : nullptr;
    #pragma unroll
    for (int s = t; s < GCHUNK; s += 256) {
        int pos = gbase + s;
        int fi;
        if (lbase) fi = (pos < nf) ? lbase[pos] : NFACES;
        else       fi = min(pos, NFACES);
        const float4* p = rast + ((size_t)b * RASTN + fi) * 3;
        sR0[s] = p[0]; sR1[s] = p[1]; sR2[s] = p[2];
    }
    __syncthreads();

    int wv = t >> 6, lane = t & 63;
    int cbase = wv * RCHUNK;
    if (gbase + cbase >= nf) return;            // whole chunk past end

    int tX = tile & 15, tY = tile >> 4;
    int col = lane & 15, row0 = lane >> 4;      // lane -> column, base row
    int pxi = tX * 16 + col;
    float px = pixc(pxi);
    float py0 = pixc(tY * 16 + row0);
    float py1 = pixc(tY * 16 + row0 + 4);
    float py2 = pixc(tY * 16 + row0 + 8);
    float py3 = pixc(tY * 16 + row0 + 12);

    float z0c = BIGF, z1c = BIGF, z2c = BIGF, z3c = BIGF;
    int j0c = -1, j1c = -1, j2c = -1, j3c = -1;

    #pragma unroll 4
    for (int j = cbase; j < cbase + RCHUNK; ++j) {
        float4 r0 = sR0[j], r1 = sR1[j], r2 = sR2[j];
        float dx  = __fsub_rn(px, r0.x);
        float Adx = __fmul_rn(r0.z, dx);        // A*dx, shared by 4 pixels
        float Cdx = __fmul_rn(r1.x, dx);        // C*dx
        auto evalp = [&](float py, float& zc, int& jc) {
            float dy = __fsub_rn(py, r0.y);
            float w0 = __fmul_rn(__fadd_rn(Adx, __fmul_rn(r0.w, dy)), r1.z);
            float w1 = __fmul_rn(__fadd_rn(Cdx, __fmul_rn(r1.y, dy)), r1.z);
            float w2 = __fsub_rn(__fsub_rn(1.0f, w0), w1);
            float d  = __fadd_rn(__fadd_rn(__fmul_rn(w0, r2.x), __fmul_rn(w1, r2.y)),
                                 __fmul_rn(w2, r2.z));
            float m  = fminf(fminf(w0, w1), w2);   // v_min3
            bool ins = (m >= 0.0f) & (d < zc);
            if (ins) { zc = d; jc = j; }
        };
        evalp(py0, z0c, j0c);
        evalp(py1, z1c, j1c);
        evalp(py2, z2c, j2c);
        evalp(py3, z3c, j3c);
    }

    auto commit = [&](int rowk, float zc, int jc) {
        if (jc >= 0) {
            int fid = __float_as_int(sR2[jc].w);
            if (fid >= 0) {
                unsigned long long pk =
                    ((unsigned long long)fsort(zc) << 32) | (unsigned int)fid;
                int pyi = tY * 16 + row0 + rowk * 4;
                atomicMin(&zbuf[((size_t)b << 16) | (pyi << 8) | pxi], pk);
            }
        }
    };
    commit(0, z0c, j0c);
    commit(1, z1c, j1c);
    commit(2, z2c, j2c);
    commit(3, z3c, j3c);
}

// ---------------------------------------------------------------------------
// Kernel 4: resolve. Per pixel: read winning fid, recompute w0,w1 from rast
// (same _rn sequence -> bit-identical), flow gather, bilinear grid sample.
// ---------------------------------------------------------------------------
__global__ __launch_bounds__(256) void resolve_kernel(
    const float4* __restrict__ rast, const float4* __restrict__ flowg,
    const unsigned long long* __restrict__ zbuf,
    const float* __restrict__ src_img, float* __restrict__ out, int B)
{
    int idx = blockIdx.x * 256 + threadIdx.x;
    if (idx >= B * HH * WW) return;
    int b = idx >> 16;
    int pix = idx & 65535;
    int pxi = pix & 255, pyi = pix >> 8;
    float px = pixc(pxi), py = pixc(pyi);

    unsigned int fid = (unsigned int)zbuf[idx];
    float fx, fy;
    if (fid != 0xFFFFFFFFu) {
        const float4* rr = rast + ((size_t)b * RASTN + fid) * 3;
        float4 r0 = rr[0], r1 = rr[1];
        float dx = __fsub_rn(px, r0.x);
        float dy = __fsub_rn(py, r0.y);
        float w0 = __fmul_rn(__fadd_rn(__fmul_rn(r0.z, dx), __fmul_rn(r0.w, dy)), r1.z);
        float w1 = __fmul_rn(__fadd_rn(__fmul_rn(r1.x, dx), __fmul_rn(r1.y, dy)), r1.z);
        float w2 = __fsub_rn(__fsub_rn(1.0f, w0), w1);
        const float4* fg = flowg + ((size_t)b * NFACES + fid) * 2;
        float4 g0 = fg[0];
        float4 g1 = fg[1];
        fx = __fadd_rn(__fadd_rn(__fmul_rn(w0, g0.x), __fmul_rn(w1, g0.z)),
                       __fmul_rn(w2, g1.x));
        fy = __fadd_rn(__fadd_rn(__fmul_rn(w0, g0.y), __fmul_rn(w1, g0.w)),
                       __fmul_rn(w2, g1.y));
    } else {
        fx = -2.0f; fy = -2.0f;
    }

    float ix = __fmul_rn(__fsub_rn(__fmul_rn(__fadd_rn(fx, 1.0f), 256.0f), 1.0f), 0.5f);
    float iy = __fmul_rn(__fsub_rn(__fmul_rn(__fadd_rn(fy, 1.0f), 256.0f), 1.0f), 0.5f);
    ix = fminf(fmaxf(ix, 0.0f), 255.0f);
    iy = fminf(fmaxf(iy, 0.0f), 255.0f);
    float x0f = floorf(ix), y0f = floorf(iy);
    float wx = __fsub_rn(ix, x0f), wy = __fsub_rn(iy, y0f);
    int x0i = (int)x0f, y0i = (int)y0f;
    int x1i = min(x0i + 1, 255), y1i = min(y0i + 1, 255);
    float omwx = __fsub_rn(1.0f, wx), omwy = __fsub_rn(1.0f, wy);
    float wa = __fmul_rn(omwx, omwy);
    float wb = __fmul_rn(wx, omwy);
    float wc = __fmul_rn(omwx, wy);
    float wd = __fmul_rn(wx, wy);
    const float* img = src_img + (size_t)b * 3 * HH * WW;
    int o00 = y0i * WW + x0i, o01 = y0i * WW + x1i;
    int o10 = y1i * WW + x0i, o11 = y1i * WW + x1i;
    float* ob = out + (size_t)b * 3 * HH * WW + (size_t)pyi * WW + pxi;
    for (int c = 0; c < 3; ++c) {
        const float* ic = img + (size_t)c * HH * WW;
        float Ia = ic[o00], Ib = ic[o01], Ic = ic[o10], Id = ic[o11];
        float val = __fadd_rn(__fadd_rn(__fadd_rn(__fmul_rn(Ia, wa), __fmul_rn(Ib, wb)),
                                        __fmul_rn(Ic, wc)),
                              __fmul_rn(Id, wd));
        ob[(size_t)c * HH * WW] = val;
    }
}

extern "C" void kernel_launch(void* const* d_in, const int* in_sizes, int n_in,
                              void* d_out, int out_size, void* d_ws, size_t ws_size,
                              hipStream_t stream)
{
    const float* src_img   = (const float*)d_in[0];
    const float* src_cam   = (const float*)d_in[1];
    const float* src_verts = (const float*)d_in[2];
    const float* tgt_cam   = (const float*)d_in[3];
    const float* tgt_verts = (const float*)d_in[4];
    const int*   faces     = (const int*)d_in[5];
    int B = in_sizes[1] / 3;   // src_cam is [B,3]

    size_t off = 0;
    auto alloc = [&](size_t bytes) {
        size_t o = off;
        off = (off + bytes + 255) & ~(size_t)255;
        return o;
    };
    size_t rastOff = alloc((size_t)B * RASTN * 3 * sizeof(float4));
    size_t flowOff = alloc((size_t)B * NFACES * 2 * sizeof(float4));
    size_t zbufOff = alloc((size_t)B * HH * WW * sizeof(unsigned long long));
    size_t cntOff  = alloc((size_t)B * 256 * sizeof(int));
    size_t listOff = alloc((size_t)B * 256 * LISTSTRIDE * sizeof(int));
    bool binned = (off <= ws_size);

    char* ws = (char*)d_ws;
    float4* rast  = (float4*)(ws + rastOff);
    float4* flowg = (float4*)(ws + flowOff);
    unsigned long long* zbuf = (unsigned long long*)(ws + zbufOff);
    int* counts = binned ? (int*)(ws + cntOff)  : nullptr;
    int* lists  = binned ? (int*)(ws + listOff) : nullptr;

    int nInit = B * HH * WW;                 // zbuf entries
    int nPre  = B * RASTN;                   // face entries
    int nMax  = nInit > nPre ? nInit : nPre;
    precompute_kernel<<<(nMax + 255) / 256, 256, 0, stream>>>(
        src_cam, src_verts, tgt_cam, tgt_verts, faces, rast, flowg, zbuf, B);
    if (binned) {
        bin_kernel<<<dim3(256, B), 256, 0, stream>>>(rast, lists, counts, B);
    }
    raster_kernel<<<dim3(B * 256, MAXGROUPS), 256, 0, stream>>>(
        rast, lists, counts, zbuf, B);
    resolve_kernel<<<(B * HH * WW + 255) / 256, 256, 0, stream>>>(
        rast, flowg, zbuf, src_img, (float*)d_out, B);
}

// Round 7
// 262.617 us; speedup vs baseline: 4.6873x; 1.0345x over previous
//
#include <hip/hip_runtime.h>

#pragma clang fp contract(off)

#define HH 256
#define WW 256
#define NVERTS 6890
#define NFACES 13776
#define RASTN (NFACES + 1)          // +1 sentinel record (depth=BIG, never wins)
#define LISTSTRIDE 13824            // multiple of 128, >= NFACES
#define RCHUNK 128                  // faces per work item (one wave)
#define MAXCH 108                   // LISTSTRIDE / RCHUNK
#define SLABS 4                     // bin blocks per tile
#define SLABSZ 3456                 // ceil(NFACES/SLABS)
#define NBLK 1024                   // persistent raster blocks (x4 waves)
#define NWAVES (NBLK * 4)
#define BIGF 1000000000.0f
#define EPSF 1e-8f

// c(i) = ((i+0.5)/256)*2 - 1  -- exact in f32, matches reference pixel coords
__device__ __forceinline__ float pixc(int i) {
    return __fsub_rn(__fmul_rn(__fdiv_rn(__fadd_rn((float)i, 0.5f), 256.0f), 2.0f), 1.0f);
}

// order-preserving float->uint (all finite values, negatives included)
__device__ __forceinline__ unsigned int fsort(float f) {
    unsigned int u = __float_as_uint(f);
    return (u & 0x80000000u) ? ~u : (u | 0x80000000u);
}

// 64-B face record layout (floats):
// [0]=x2 [1]=y2 [2]=A [3]=B [4]=C [5]=D [6]=inv [7]=fid [8]=z0 [9]=z1 [10]=z2
// Degenerate / sentinel: A=B=C=D=0, inv=1 -> w0=w1=0,w2=1, depth = exactly BIG
// -> never wins strict-<, identical to ref's inside &= |denom|>=EPS.

// ---------------------------------------------------------------------------
// Kernel 1: precompute 64-B records + flow verts; zbuf init; control zero-init.
// ---------------------------------------------------------------------------
__global__ __launch_bounds__(256) void precompute_kernel(
    const float* __restrict__ src_cam, const float* __restrict__ src_verts,
    const float* __restrict__ tgt_cam, const float* __restrict__ tgt_verts,
    const int* __restrict__ faces,
    float4* __restrict__ rast64, float4* __restrict__ flowg,
    unsigned long long* __restrict__ zbuf,
    int* __restrict__ counts, int* __restrict__ done, int* __restrict__ qcount,
    int B)
{
    int idx = blockIdx.x * blockDim.x + threadIdx.x;
    if (idx < B * HH * WW) zbuf[idx] = ~0ull;   // background sentinel
    if (counts && idx < B * 256) { counts[idx] = 0; done[idx] = 0; }
    if (qcount && idx == 0) qcount[0] = 0;
    if (idx >= B * RASTN) return;
    int b = idx / RASTN;
    int f = idx - b * RASTN;
    float4* rr = rast64 + ((size_t)b * RASTN + f) * 4;
    if (f == NFACES) {   // sentinel record
        rr[0] = make_float4(0.0f, 0.0f, 0.0f, 0.0f);
        rr[1] = make_float4(0.0f, 1.0f, 0.0f, __int_as_float(-1));  // C,D=0... see below
        // careful: layout is [4]=C [5]=D [6]=inv [7]=fid
        rr[1] = make_float4(0.0f, 0.0f, 1.0f, __int_as_float(-1));
        rr[2] = make_float4(BIGF, BIGF, BIGF, 0.0f);
        rr[3] = make_float4(0.0f, 0.0f, 0.0f, 0.0f);
        return;
    }
    int i0 = faces[3*f+0], i1 = faces[3*f+1], i2 = faces[3*f+2];

    float tc0 = tgt_cam[3*b+0], tc1 = tgt_cam[3*b+1], tc2 = tgt_cam[3*b+2];
    const float* tv = tgt_verts + (size_t)b * NVERTS * 3;
    float x0 = __fmul_rn(tc0, __fadd_rn(tv[3*i0+0], tc1));
    float y0 = -__fmul_rn(tc0, __fadd_rn(tv[3*i0+1], tc2));
    float z0 = tv[3*i0+2];
    float x1 = __fmul_rn(tc0, __fadd_rn(tv[3*i1+0], tc1));
    float y1 = -__fmul_rn(tc0, __fadd_rn(tv[3*i1+1], tc2));
    float z1 = tv[3*i1+2];
    float x2 = __fmul_rn(tc0, __fadd_rn(tv[3*i2+0], tc1));
    float y2 = -__fmul_rn(tc0, __fadd_rn(tv[3*i2+1], tc2));
    float z2 = tv[3*i2+2];

    float A  = __fsub_rn(y1, y2);
    float D  = __fsub_rn(x0, x2);
    float Bc = __fsub_rn(x2, x1);
    float E  = __fsub_rn(y0, y2);
    float denom = __fadd_rn(__fmul_rn(A, D), __fmul_rn(Bc, E));
    bool valid = (fabsf(denom) >= EPSF);
    float inv = __fdiv_rn(1.0f, valid ? denom : 1.0f);
    float Cc = __fsub_rn(y2, y0);

    if (valid) {
        rr[0] = make_float4(x2, y2, A, Bc);
        rr[1] = make_float4(Cc, D, inv, __int_as_float(f));
        rr[2] = make_float4(z0, z1, z2, 0.0f);
    } else {
        rr[0] = make_float4(0.0f, 0.0f, 0.0f, 0.0f);
        rr[1] = make_float4(0.0f, 0.0f, 1.0f, __int_as_float(f));
        rr[2] = make_float4(BIGF, BIGF, BIGF, 0.0f);
    }
    rr[3] = make_float4(0.0f, 0.0f, 0.0f, 0.0f);

    float sc0 = src_cam[3*b+0], sc1 = src_cam[3*b+1], sc2 = src_cam[3*b+2];
    const float* sv = src_verts + (size_t)b * NVERTS * 3;
    float g0x = __fmul_rn(sc0, __fadd_rn(sv[3*i0+0], sc1));
    float g0y = __fmul_rn(sc0, __fadd_rn(sv[3*i0+1], sc2));
    float g1x = __fmul_rn(sc0, __fadd_rn(sv[3*i1+0], sc1));
    float g1y = __fmul_rn(sc0, __fadd_rn(sv[3*i1+1], sc2));
    float g2x = __fmul_rn(sc0, __fadd_rn(sv[3*i2+0], sc1));
    float g2y = __fmul_rn(sc0, __fadd_rn(sv[3*i2+1], sc2));
    size_t fo = ((size_t)b * NFACES + f) * 2;
    flowg[fo+0] = make_float4(g0x, g0y, g1x, g1y);
    flowg[fo+1] = make_float4(g2x, g2y, 0.0f, 0.0f);
}

// ---------------------------------------------------------------------------
// Kernel 2: bin. Unordered per-wave atomic compaction (order-independent
// because the raster merge is an atomicMin on (depth,fid)): no __syncthreads
// in the scan. SLABS blocks per tile, each culls its face slab with the
// interval-arithmetic test (1e-6-relative margins, conservative for slivers)
// and appends indices via one atomicAdd per wave. The LAST finishing slab
// (device-scope done counter) pads the list to x128 with the sentinel face
// and enqueues (tileG,chunk) work items.
// ---------------------------------------------------------------------------
__global__ __launch_bounds__(256) void bin_kernel(
    const float4* __restrict__ rast64, int* __restrict__ lists,
    int* __restrict__ counts, int* __restrict__ done,
    unsigned int* __restrict__ queue, int* __restrict__ qcount, int B)
{
    int tile = blockIdx.x;          // 0..255
    int slab = blockIdx.y;
    int b = blockIdx.z;
    int tileG = b * 256 + tile;
    int tX = tile & 15, tY = tile >> 4;
    float txmin = pixc(tX * 16), txmax = pixc(tX * 16 + 15);
    float tymin = pixc(tY * 16), tymax = pixc(tY * 16 + 15);

    int lane = threadIdx.x & 63;
    const float4* rb = rast64 + (size_t)b * RASTN * 4;
    int* mylist = lists + (size_t)tileG * LISTSTRIDE;
    int lo = slab * SLABSZ;
    int hi = min(lo + SLABSZ, NFACES);

    for (int f = lo + threadIdx.x; f < hi; f += 256) {
        float4 r0 = rb[(size_t)f*4+0];
        float4 r1 = rb[(size_t)f*4+1];
        float dx0 = txmin - r0.x, dx1 = txmax - r0.x;
        float dy0 = tymin - r0.y, dy1 = tymax - r0.y;
        float mx = fmaxf(fabsf(dx0), fabsf(dx1));
        float my = fmaxf(fabsf(dy0), fabsf(dy1));
        float inv = r1.z, ainv = fabsf(inv);
        float t0max = fmaxf(r0.z*dx0, r0.z*dx1) + fmaxf(r0.w*dy0, r0.w*dy1);
        float t0min = fminf(r0.z*dx0, r0.z*dx1) + fminf(r0.w*dy0, r0.w*dy1);
        float w0max = fmaxf(t0max*inv, t0min*inv);
        float w0min = fminf(t0max*inv, t0min*inv);
        float am0 = fabsf(r0.z)*mx + fabsf(r0.w)*my;
        float M0 = 1e-6f * (am0*ainv + 1.0f + fmaxf(fabsf(w0max), fabsf(w0min)));
        float t1max = fmaxf(r1.x*dx0, r1.x*dx1) + fmaxf(r1.y*dy0, r1.y*dy1);
        float t1min = fminf(r1.x*dx0, r1.x*dx1) + fminf(r1.y*dy0, r1.y*dy1);
        float w1max = fmaxf(t1max*inv, t1min*inv);
        float w1min = fminf(t1max*inv, t1min*inv);
        float am1 = fabsf(r1.x)*mx + fabsf(r1.y)*my;
        float M1 = 1e-6f * (am1*ainv + 1.0f + fmaxf(fabsf(w1max), fabsf(w1min)));
        float M2 = M0 + M1 + 1e-6f * (1.0f + fabsf(w0min) + fabsf(w1min));
        float w2max = 1.0f - w0min - w1min + M2;
        bool pass = (w0max + M0 >= 0.0f) && (w1max + M1 >= 0.0f) && (w2max >= 0.0f);

        unsigned long long m = __ballot(pass);
        int cnt = __popcll(m);
        if (cnt) {
            int wbase = 0;
            if (lane == 0) wbase = atomicAdd(&counts[tileG], cnt);
            wbase = __shfl(wbase, 0);
            if (pass) {
                int pre = __popcll(m & ((1ull << lane) - 1ull));
                mylist[wbase + pre] = f;
            }
        }
    }

    __syncthreads();
    if (threadIdx.x == 0) {
        __threadfence();                      // counts-adds visible before done
        if (atomicAdd(&done[tileG], 1) == SLABS - 1) {
            int cnt = atomicAdd(&counts[tileG], 0);   // coherent read
            int padded = (cnt + RCHUNK - 1) & ~(RCHUNK - 1);
            for (int i = cnt; i < padded; ++i) mylist[i] = NFACES;
            int nch = padded >> 7;
            if (nch) {
                int qb = atomicAdd(qcount, nch);
                for (int kk = 0; kk < nch; ++kk)
                    queue[qb + kk] = ((unsigned int)tileG << 8) | (unsigned int)kk;
            }
        }
    }
}

// ---------------------------------------------------------------------------
// Kernel 3: raster. 4096 persistent waves grid-stride the work queue; each
// entry = (tileG, 128-face chunk). NO LDS: face indices load as uniform int4
// (scalar pipe), face records as uniform 64-B s_loads from rast64 (fid
// embedded). Each lane owns 4 pixels of the 16x16 tile sharing one column
// (dx, A*dx, C*dx computed once per face, bit-identical reuse). Per-pixel
// u64 atomicMin of (sortable_depth, fid) == exact lexicographic min ==
// reference's first-argmin + strict-< semantics. All depth math _rn,
// no FMA contraction -> bit-identical to the f32 reference.
// ---------------------------------------------------------------------------
__global__ __launch_bounds__(256) void raster_kernel(
    const float* __restrict__ rast64, const int* __restrict__ lists,
    const unsigned int* __restrict__ queue, const int* __restrict__ qcount,
    unsigned long long* __restrict__ zbuf, int B)
{
    int wv = threadIdx.x >> 6, lane = threadIdx.x & 63;
    int waveId = blockIdx.x * 4 + wv;
    int qn = queue ? qcount[0] : B * 256 * MAXCH;
    qn = __builtin_amdgcn_readfirstlane(qn);

    for (int e = waveId; e < qn; e += NWAVES) {
        int tileG, k;
        if (queue) {
            unsigned int ent = queue[e];
            tileG = (int)(ent >> 8); k = (int)(ent & 255u);
        } else {
            tileG = e / MAXCH; k = e - tileG * MAXCH;
        }
        tileG = __builtin_amdgcn_readfirstlane(tileG);
        k = __builtin_amdgcn_readfirstlane(k);
        int b = tileG >> 8, tile = tileG & 255;
        const int* lp = lists ? (lists + (size_t)tileG * LISTSTRIDE + k * RCHUNK)
                              : nullptr;
        const float* rb = rast64 + (size_t)b * RASTN * 16;

        int tX = tile & 15, tY = tile >> 4;
        int col = lane & 15, row0 = lane >> 4;
        int pxi = tX * 16 + col;
        float px = pixc(pxi);
        float py0 = pixc(tY * 16 + row0);
        float py1 = pixc(tY * 16 + row0 + 4);
        float py2 = pixc(tY * 16 + row0 + 8);
        float py3 = pixc(tY * 16 + row0 + 12);

        float z0c = BIGF, z1c = BIGF, z2c = BIGF, z3c = BIGF;
        int f0c = -1, f1c = -1, f2c = -1, f3c = -1;

        for (int j = 0; j < RCHUNK; j += 4) {
            int4 fis;
            if (lp) {
                fis = *(const int4*)(lp + j);
            } else {
                int base = k * RCHUNK + j;
                fis.x = min(base + 0, NFACES); fis.y = min(base + 1, NFACES);
                fis.z = min(base + 2, NFACES); fis.w = min(base + 3, NFACES);
            }
            #pragma unroll
            for (int q = 0; q < 4; ++q) {
                int fi = (q == 0) ? fis.x : (q == 1) ? fis.y : (q == 2) ? fis.z : fis.w;
                fi = __builtin_amdgcn_readfirstlane(fi);
                const float* r = rb + (size_t)fi * 16;
                float X2 = r[0], Y2 = r[1], A = r[2], Bc = r[3];
                float Cc = r[4], Dd = r[5], inv = r[6];
                int   fid = __float_as_int(r[7]);
                float Z0 = r[8], Z1 = r[9], Z2 = r[10];

                float dx  = __fsub_rn(px, X2);
                float Adx = __fmul_rn(A, dx);
                float Cdx = __fmul_rn(Cc, dx);
                auto evalp = [&](float py, float& zc, int& fc) {
                    float dy = __fsub_rn(py, Y2);
                    float w0 = __fmul_rn(__fadd_rn(Adx, __fmul_rn(Bc, dy)), inv);
                    float w1 = __fmul_rn(__fadd_rn(Cdx, __fmul_rn(Dd, dy)), inv);
                    float w2 = __fsub_rn(__fsub_rn(1.0f, w0), w1);
                    float d  = __fadd_rn(__fadd_rn(__fmul_rn(w0, Z0), __fmul_rn(w1, Z1)),
                                         __fmul_rn(w2, Z2));
                    float mm = fminf(fminf(w0, w1), w2);    // v_min3
                    bool ins = (mm >= 0.0f) & (d < zc);
                    if (ins) { zc = d; fc = fid; }
                };
                evalp(py0, z0c, f0c);
                evalp(py1, z1c, f1c);
                evalp(py2, z2c, f2c);
                evalp(py3, z3c, f3c);
            }
        }

        auto commit = [&](int rowk, float zc, int fc) {
            if (fc >= 0) {
                unsigned long long pk =
                    ((unsigned long long)fsort(zc) << 32) | (unsigned int)fc;
                int pyi = tY * 16 + row0 + rowk * 4;
                atomicMin(&zbuf[((size_t)b << 16) | (pyi << 8) | pxi], pk);
            }
        };
        commit(0, z0c, f0c);
        commit(1, z1c, f1c);
        commit(2, z2c, f2c);
        commit(3, z3c, f3c);
    }
}

// ---------------------------------------------------------------------------
// Kernel 4: resolve. Per pixel: read winning fid, recompute w0,w1 from the
// record (same _rn sequence -> bit-identical), flow gather, bilinear sample.
// ---------------------------------------------------------------------------
__global__ __launch_bounds__(256) void resolve_kernel(
    const float* __restrict__ rast64, const float4* __restrict__ flowg,
    const unsigned long long* __restrict__ zbuf,
    const float* __restrict__ src_img, float* __restrict__ out, int B)
{
    int idx = blockIdx.x * 256 + threadIdx.x;
    if (idx >= B * HH * WW) return;
    int b = idx >> 16;
    int pix = idx & 65535;
    int pxi = pix & 255, pyi = pix >> 8;
    float px = pixc(pxi), py = pixc(pyi);

    unsigned int fid = (unsigned int)zbuf[idx];
    float fx, fy;
    if (fid != 0xFFFFFFFFu) {
        const float* r = rast64 + ((size_t)b * RASTN + fid) * 16;
        float dx = __fsub_rn(px, r[0]);
        float dy = __fsub_rn(py, r[1]);
        float w0 = __fmul_rn(__fadd_rn(__fmul_rn(r[2], dx), __fmul_rn(r[3], dy)), r[6]);
        float w1 = __fmul_rn(__fadd_rn(__fmul_rn(r[4], dx), __fmul_rn(r[5], dy)), r[6]);
        float w2 = __fsub_rn(__fsub_rn(1.0f, w0), w1);
        const float4* fg = flowg + ((size_t)b * NFACES + fid) * 2;
        float4 g0 = fg[0];
        float4 g1 = fg[1];
        fx = __fadd_rn(__fadd_rn(__fmul_rn(w0, g0.x), __fmul_rn(w1, g0.z)),
                       __fmul_rn(w2, g1.x));
        fy = __fadd_rn(__fadd_rn(__fmul_rn(w0, g0.y), __fmul_rn(w1, g0.w)),
                       __fmul_rn(w2, g1.y));
    } else {
        fx = -2.0f; fy = -2.0f;
    }

    float ix = __fmul_rn(__fsub_rn(__fmul_rn(__fadd_rn(fx, 1.0f), 256.0f), 1.0f), 0.5f);
    float iy = __fmul_rn(__fsub_rn(__fmul_rn(__fadd_rn(fy, 1.0f), 256.0f), 1.0f), 0.5f);
    ix = fminf(fmaxf(ix, 0.0f), 255.0f);
    iy = fminf(fmaxf(iy, 0.0f), 255.0f);
    float x0f = floorf(ix), y0f = floorf(iy);
    float wx = __fsub_rn(ix, x0f), wy = __fsub_rn(iy, y0f);
    int x0i = (int)x0f, y0i = (int)y0f;
    int x1i = min(x0i + 1, 255), y1i = min(y0i + 1, 255);
    float omwx = __fsub_rn(1.0f, wx), omwy = __fsub_rn(1.0f, wy);
    float wa = __fmul_rn(omwx, omwy);
    float wb = __fmul_rn(wx, omwy);
    float wc = __fmul_rn(omwx, wy);
    float wd = __fmul_rn(wx, wy);
    const float* img = src_img + (size_t)b * 3 * HH * WW;
    int o00 = y0i * WW + x0i, o01 = y0i * WW + x1i;
    int o10 = y1i * WW + x0i, o11 = y1i * WW + x1i;
    float* ob = out + (size_t)b * 3 * HH * WW + (size_t)pyi * WW + pxi;
    for (int c = 0; c < 3; ++c) {
        const float* ic = img + (size_t)c * HH * WW;
        float Ia = ic[o00], Ib = ic[o01], Ic = ic[o10], Id = ic[o11];
        float val = __fadd_rn(__fadd_rn(__fadd_rn(__fmul_rn(Ia, wa), __fmul_rn(Ib, wb)),
                                        __fmul_rn(Ic, wc)),
                              __fmul_rn(Id, wd));
        ob[(size_t)c * HH * WW] = val;
    }
}

extern "C" void kernel_launch(void* const* d_in, const int* in_sizes, int n_in,
                              void* d_out, int out_size, void* d_ws, size_t ws_size,
                              hipStream_t stream)
{
    const float* src_img   = (const float*)d_in[0];
    const float* src_cam   = (const float*)d_in[1];
    const float* src_verts = (const float*)d_in[2];
    const float* tgt_cam   = (const float*)d_in[3];
    const float* tgt_verts = (const float*)d_in[4];
    const int*   faces     = (const int*)d_in[5];
    int B = in_sizes[1] / 3;   // src_cam is [B,3]

    size_t off = 0;
    auto alloc = [&](size_t bytes) {
        size_t o = off;
        off = (off + bytes + 255) & ~(size_t)255;
        return o;
    };
    size_t rastOff = alloc((size_t)B * RASTN * 64);
    size_t flowOff = alloc((size_t)B * NFACES * 2 * sizeof(float4));
    size_t zbufOff = alloc((size_t)B * HH * WW * sizeof(unsigned long long));
    size_t cntOff  = alloc((size_t)B * 256 * sizeof(int));
    size_t donOff  = alloc((size_t)B * 256 * sizeof(int));
    size_t qcOff   = alloc(sizeof(int));
    size_t quOff   = alloc((size_t)B * 256 * MAXCH * sizeof(unsigned int));
    size_t listOff = alloc((size_t)B * 256 * LISTSTRIDE * sizeof(int));
    bool binned = (off <= ws_size);

    char* ws = (char*)d_ws;
    float4* rast64 = (float4*)(ws + rastOff);
    float4* flowg  = (float4*)(ws + flowOff);
    unsigned long long* zbuf = (unsigned long long*)(ws + zbufOff);
    int* counts = binned ? (int*)(ws + cntOff) : nullptr;
    int* done   = binned ? (int*)(ws + donOff) : nullptr;
    int* qcount = binned ? (int*)(ws + qcOff)  : nullptr;
    unsigned int* queue = binned ? (unsigned int*)(ws + quOff) : nullptr;
    int* lists  = binned ? (int*)(ws + listOff) : nullptr;

    int nInit = B * HH * WW;
    int nPre  = B * RASTN;
    int nMax  = nInit > nPre ? nInit : nPre;
    precompute_kernel<<<(nMax + 255) / 256, 256, 0, stream>>>(
        src_cam, src_verts, tgt_cam, tgt_verts, faces,
        rast64, flowg, zbuf, counts, done, qcount, B);
    if (binned) {
        bin_kernel<<<dim3(256, SLABS, B), 256, 0, stream>>>(
            rast64, lists, counts, done, queue, qcount, B);
    }
    raster_kernel<<<NBLK, 256, 0, stream>>>(
        (const float*)rast64, lists, queue, qcount, zbuf, B);
    resolve_kernel<<<(B * HH * WW + 255) / 256, 256, 0, stream>>>(
        (const float*)rast64, flowg, zbuf, src_img, (float*)d_out, B);
}

// Round 8
// 229.168 us; speedup vs baseline: 5.3714x; 1.1460x over previous
//
#include <hip/hip_runtime.h>

#pragma clang fp contract(off)

#define HH 256
#define WW 256
#define NVERTS 6890
#define NFACES 13776
#define RASTN (NFACES + 1)          // +1 sentinel record (depth=BIG, never wins)
#define LISTSTRIDE 13824            // multiple of 128, >= NFACES
#define RCHUNK 128                  // faces per work item (one wave)
#define MAXCH 108                   // LISTSTRIDE / RCHUNK
#define SLABS 4                     // bin blocks per tile
#define SLABSZ 3456                 // ceil(NFACES/SLABS)
#define NBLK 1024                   // persistent raster blocks (x4 waves)
#define NWAVES (NBLK * 4)
#define BIGF 1000000000.0f
#define EPSF 1e-8f

// c(i) = ((i+0.5)/256)*2 - 1  -- exact in f32, matches reference pixel coords
__device__ __forceinline__ float pixc(int i) {
    return __fsub_rn(__fmul_rn(__fdiv_rn(__fadd_rn((float)i, 0.5f), 256.0f), 2.0f), 1.0f);
}

// order-preserving float->uint (all finite values, negatives included)
__device__ __forceinline__ unsigned int fsort(float f) {
    unsigned int u = __float_as_uint(f);
    return (u & 0x80000000u) ? ~u : (u | 0x80000000u);
}

// 64-B face record layout (floats):
// [0]=x2 [1]=y2 [2]=A [3]=B [4]=C [5]=D [6]=inv [7]=fid [8]=z0 [9]=z1 [10]=z2
// Degenerate / sentinel: A=B=C=D=0, inv=1 -> w0=w1=0,w2=1, depth = exactly BIG
// -> never wins strict-<, identical to ref's inside &= |denom|>=EPS.

// ---------------------------------------------------------------------------
// Kernel 1: precompute 64-B records + conservative bbox + flow verts; zbuf
// init; control zero-init.
// bbox = vertex bbox inflated by  E + slop + 1e-4  where
//   slop = 32eps * S   (S = max coordinate scale; perpendicular rounding slop
//                       of the reference's rounded inside-test, denom-indep)
//   E = slop * max(|ei||ej|) / |denom|   (along-sliver extension: computed-
//       inside region of near-parallel edge pairs is a strip ~slop/sin(phi),
//       sin(phi) = |denom|/(|ei||ej|))
// Invalid faces (|denom|<EPS): empty bbox -> excluded from all lists (they
// can never win the strict-< z-test in the reference either).
// ---------------------------------------------------------------------------
__global__ __launch_bounds__(256) void precompute_kernel(
    const float* __restrict__ src_cam, const float* __restrict__ src_verts,
    const float* __restrict__ tgt_cam, const float* __restrict__ tgt_verts,
    const int* __restrict__ faces,
    float4* __restrict__ rast64, float4* __restrict__ bbox,
    float4* __restrict__ flowg,
    unsigned long long* __restrict__ zbuf,
    int* __restrict__ counts, int* __restrict__ done, int* __restrict__ qcount,
    int B)
{
    int idx = blockIdx.x * blockDim.x + threadIdx.x;
    if (idx < B * HH * WW) zbuf[idx] = ~0ull;   // background sentinel
    if (counts && idx < B * 256) { counts[idx] = 0; done[idx] = 0; }
    if (qcount && idx == 0) qcount[0] = 0;
    if (idx >= B * RASTN) return;
    int b = idx / RASTN;
    int f = idx - b * RASTN;
    float4* rr = rast64 + ((size_t)b * RASTN + f) * 4;
    if (f == NFACES) {   // sentinel record
        rr[0] = make_float4(0.0f, 0.0f, 0.0f, 0.0f);
        rr[1] = make_float4(0.0f, 0.0f, 1.0f, __int_as_float(-1));
        rr[2] = make_float4(BIGF, BIGF, BIGF, 0.0f);
        rr[3] = make_float4(0.0f, 0.0f, 0.0f, 0.0f);
        return;
    }
    int i0 = faces[3*f+0], i1 = faces[3*f+1], i2 = faces[3*f+2];

    float tc0 = tgt_cam[3*b+0], tc1 = tgt_cam[3*b+1], tc2 = tgt_cam[3*b+2];
    const float* tv = tgt_verts + (size_t)b * NVERTS * 3;
    float x0 = __fmul_rn(tc0, __fadd_rn(tv[3*i0+0], tc1));
    float y0 = -__fmul_rn(tc0, __fadd_rn(tv[3*i0+1], tc2));
    float z0 = tv[3*i0+2];
    float x1 = __fmul_rn(tc0, __fadd_rn(tv[3*i1+0], tc1));
    float y1 = -__fmul_rn(tc0, __fadd_rn(tv[3*i1+1], tc2));
    float z1 = tv[3*i1+2];
    float x2 = __fmul_rn(tc0, __fadd_rn(tv[3*i2+0], tc1));
    float y2 = -__fmul_rn(tc0, __fadd_rn(tv[3*i2+1], tc2));
    float z2 = tv[3*i2+2];

    float A  = __fsub_rn(y1, y2);
    float D  = __fsub_rn(x0, x2);
    float Bc = __fsub_rn(x2, x1);
    float E_ = __fsub_rn(y0, y2);
    float denom = __fadd_rn(__fmul_rn(A, D), __fmul_rn(Bc, E_));
    bool valid = (fabsf(denom) >= EPSF);
    float inv = __fdiv_rn(1.0f, valid ? denom : 1.0f);
    float Cc = __fsub_rn(y2, y0);

    if (valid) {
        rr[0] = make_float4(x2, y2, A, Bc);
        rr[1] = make_float4(Cc, D, inv, __int_as_float(f));
        rr[2] = make_float4(z0, z1, z2, 0.0f);
    } else {
        rr[0] = make_float4(0.0f, 0.0f, 0.0f, 0.0f);
        rr[1] = make_float4(0.0f, 0.0f, 1.0f, __int_as_float(f));
        rr[2] = make_float4(BIGF, BIGF, BIGF, 0.0f);
    }
    rr[3] = make_float4(0.0f, 0.0f, 0.0f, 0.0f);

    // conservative bbox
    float4 bb;
    if (valid) {
        float xmn = fminf(fminf(x0, x1), x2), xmx = fmaxf(fmaxf(x0, x1), x2);
        float ymn = fminf(fminf(y0, y1), y2), ymx = fmaxf(fmaxf(y0, y1), y2);
        float S = fmaxf(fmaxf(fabsf(xmn), fabsf(xmx)),
                        fmaxf(fabsf(ymn), fabsf(ymx))) + 1.01f;
        float slop = 2e-6f * S;                       // ~32 eps * S
        float l0 = sqrtf(D*D + E_*E_);                // |v0-v2|
        float dx1v = x1 - x2, dy1v = y1 - y2;
        float l1 = sqrtf(dx1v*dx1v + dy1v*dy1v);      // |v1-v2|
        float dx2v = x1 - x0, dy2v = y1 - y0;
        float l2 = sqrtf(dx2v*dx2v + dy2v*dy2v);      // |v1-v0|
        float mp = fmaxf(fmaxf(l0*l1, l1*l2), l0*l2);
        float Ex = slop * mp / fabsf(denom);          // sliver extension
        float m = Ex + slop + 1e-4f;
        bb = make_float4(xmn - m, ymn - m, xmx + m, ymx + m);
    } else {
        bb = make_float4(2e9f, 2e9f, -2e9f, -2e9f);   // empty
    }
    bbox[(size_t)b * NFACES + f] = bb;

    float sc0 = src_cam[3*b+0], sc1 = src_cam[3*b+1], sc2 = src_cam[3*b+2];
    const float* sv = src_verts + (size_t)b * NVERTS * 3;
    float g0x = __fmul_rn(sc0, __fadd_rn(sv[3*i0+0], sc1));
    float g0y = __fmul_rn(sc0, __fadd_rn(sv[3*i0+1], sc2));
    float g1x = __fmul_rn(sc0, __fadd_rn(sv[3*i1+0], sc1));
    float g1y = __fmul_rn(sc0, __fadd_rn(sv[3*i1+1], sc2));
    float g2x = __fmul_rn(sc0, __fadd_rn(sv[3*i2+0], sc1));
    float g2y = __fmul_rn(sc0, __fadd_rn(sv[3*i2+1], sc2));
    size_t fo = ((size_t)b * NFACES + f) * 2;
    flowg[fo+0] = make_float4(g0x, g0y, g1x, g1y);
    flowg[fo+1] = make_float4(g2x, g2y, 0.0f, 0.0f);
}

// ---------------------------------------------------------------------------
// Kernel 2: bin. Cheap bbox-overlap test on a coalesced 16 B/face load.
// Unordered per-wave atomic compaction (order-independent because the raster
// merge is an atomicMin on (depth,fid)). SLABS blocks per tile; the LAST
// finishing slab (device-scope done counter) pads the list to x128 with the
// sentinel face and enqueues (tileG,chunk) work items.
// ---------------------------------------------------------------------------
__global__ __launch_bounds__(256) void bin_kernel(
    const float4* __restrict__ bbox, int* __restrict__ lists,
    int* __restrict__ counts, int* __restrict__ done,
    unsigned int* __restrict__ queue, int* __restrict__ qcount, int B)
{
    int tile = blockIdx.x;          // 0..255
    int slab = blockIdx.y;
    int b = blockIdx.z;
    int tileG = b * 256 + tile;
    int tX = tile & 15, tY = tile >> 4;
    float txmin = pixc(tX * 16), txmax = pixc(tX * 16 + 15);
    float tymin = pixc(tY * 16), tymax = pixc(tY * 16 + 15);

    int lane = threadIdx.x & 63;
    const float4* bbs = bbox + (size_t)b * NFACES;
    int* mylist = lists + (size_t)tileG * LISTSTRIDE;
    int lo = slab * SLABSZ;
    int hi = min(lo + SLABSZ, NFACES);

    for (int f = lo + threadIdx.x; f < hi; f += 256) {
        float4 bb = bbs[f];
        bool pass = (bb.x <= txmax) & (bb.z >= txmin) &
                    (bb.y <= tymax) & (bb.w >= tymin);
        unsigned long long m = __ballot(pass);
        int cnt = __popcll(m);
        if (cnt) {
            int wbase = 0;
            if (lane == 0) wbase = atomicAdd(&counts[tileG], cnt);
            wbase = __shfl(wbase, 0);
            if (pass) {
                int pre = __popcll(m & ((1ull << lane) - 1ull));
                mylist[wbase + pre] = f;
            }
        }
    }

    __syncthreads();
    if (threadIdx.x == 0) {
        __threadfence();                      // counts-adds visible before done
        if (atomicAdd(&done[tileG], 1) == SLABS - 1) {
            int cnt = atomicAdd(&counts[tileG], 0);   // coherent read
            int padded = (cnt + RCHUNK - 1) & ~(RCHUNK - 1);
            for (int i = cnt; i < padded; ++i) mylist[i] = NFACES;
            int nch = padded >> 7;
            if (nch) {
                int qb = atomicAdd(qcount, nch);
                for (int kk = 0; kk < nch; ++kk)
                    queue[qb + kk] = ((unsigned int)tileG << 8) | (unsigned int)kk;
            }
        }
    }
}

// ---------------------------------------------------------------------------
// Kernel 3: raster. 4096 persistent waves grid-stride the work queue; each
// entry = (tileG, 128-face chunk). NO LDS: face indices load as uniform int4
// (scalar pipe), face records as uniform 64-B s_loads from rast64 (fid
// embedded). Each lane owns 4 pixels of the 16x16 tile sharing one column
// (dx, A*dx, C*dx computed once per face, bit-identical reuse). Per-pixel
// u64 atomicMin of (sortable_depth, fid) == exact lexicographic min ==
// reference's first-argmin + strict-< semantics. All depth math _rn,
// no FMA contraction -> bit-identical to the f32 reference.
// ---------------------------------------------------------------------------
__global__ __launch_bounds__(256) void raster_kernel(
    const float* __restrict__ rast64, const int* __restrict__ lists,
    const unsigned int* __restrict__ queue, const int* __restrict__ qcount,
    unsigned long long* __restrict__ zbuf, int B)
{
    int wv = threadIdx.x >> 6, lane = threadIdx.x & 63;
    int waveId = blockIdx.x * 4 + wv;
    int qn = queue ? qcount[0] : B * 256 * MAXCH;
    qn = __builtin_amdgcn_readfirstlane(qn);

    for (int e = waveId; e < qn; e += NWAVES) {
        int tileG, k;
        if (queue) {
            unsigned int ent = queue[e];
            tileG = (int)(ent >> 8); k = (int)(ent & 255u);
        } else {
            tileG = e / MAXCH; k = e - tileG * MAXCH;
        }
        tileG = __builtin_amdgcn_readfirstlane(tileG);
        k = __builtin_amdgcn_readfirstlane(k);
        int b = tileG >> 8, tile = tileG & 255;
        const int* lp = lists ? (lists + (size_t)tileG * LISTSTRIDE + k * RCHUNK)
                              : nullptr;
        const float* rb = rast64 + (size_t)b * RASTN * 16;

        int tX = tile & 15, tY = tile >> 4;
        int col = lane & 15, row0 = lane >> 4;
        int pxi = tX * 16 + col;
        float px = pixc(pxi);
        float py0 = pixc(tY * 16 + row0);
        float py1 = pixc(tY * 16 + row0 + 4);
        float py2 = pixc(tY * 16 + row0 + 8);
        float py3 = pixc(tY * 16 + row0 + 12);

        float z0c = BIGF, z1c = BIGF, z2c = BIGF, z3c = BIGF;
        int f0c = -1, f1c = -1, f2c = -1, f3c = -1;

        for (int j = 0; j < RCHUNK; j += 4) {
            int4 fis;
            if (lp) {
                fis = *(const int4*)(lp + j);
            } else {
                int base = k * RCHUNK + j;
                fis.x = min(base + 0, NFACES); fis.y = min(base + 1, NFACES);
                fis.z = min(base + 2, NFACES); fis.w = min(base + 3, NFACES);
            }
            #pragma unroll
            for (int q = 0; q < 4; ++q) {
                int fi = (q == 0) ? fis.x : (q == 1) ? fis.y : (q == 2) ? fis.z : fis.w;
                fi = __builtin_amdgcn_readfirstlane(fi);
                const float* r = rb + (size_t)fi * 16;
                float X2 = r[0], Y2 = r[1], A = r[2], Bc = r[3];
                float Cc = r[4], Dd = r[5], inv = r[6];
                int   fid = __float_as_int(r[7]);
                float Z0 = r[8], Z1 = r[9], Z2 = r[10];

                float dx  = __fsub_rn(px, X2);
                float Adx = __fmul_rn(A, dx);
                float Cdx = __fmul_rn(Cc, dx);
                auto evalp = [&](float py, float& zc, int& fc) {
                    float dy = __fsub_rn(py, Y2);
                    float w0 = __fmul_rn(__fadd_rn(Adx, __fmul_rn(Bc, dy)), inv);
                    float w1 = __fmul_rn(__fadd_rn(Cdx, __fmul_rn(Dd, dy)), inv);
                    float w2 = __fsub_rn(__fsub_rn(1.0f, w0), w1);
                    float d  = __fadd_rn(__fadd_rn(__fmul_rn(w0, Z0), __fmul_rn(w1, Z1)),
                                         __fmul_rn(w2, Z2));
                    float mm = fminf(fminf(w0, w1), w2);    // v_min3
                    bool ins = (mm >= 0.0f) & (d < zc);
                    if (ins) { zc = d; fc = fid; }
                };
                evalp(py0, z0c, f0c);
                evalp(py1, z1c, f1c);
                evalp(py2, z2c, f2c);
                evalp(py3, z3c, f3c);
            }
        }

        auto commit = [&](int rowk, float zc, int fc) {
            if (fc >= 0) {
                unsigned long long pk =
                    ((unsigned long long)fsort(zc) << 32) | (unsigned int)fc;
                int pyi = tY * 16 + row0 + rowk * 4;
                atomicMin(&zbuf[((size_t)b << 16) | (pyi << 8) | pxi], pk);
            }
        };
        commit(0, z0c, f0c);
        commit(1, z1c, f1c);
        commit(2, z2c, f2c);
        commit(3, z3c, f3c);
    }
}

// ---------------------------------------------------------------------------
// Kernel 4: resolve. Per pixel: read winning fid, recompute w0,w1 from the
// record (same _rn sequence -> bit-identical), flow gather, bilinear sample.
// ---------------------------------------------------------------------------
__global__ __launch_bounds__(256) void resolve_kernel(
    const float* __restrict__ rast64, const float4* __restrict__ flowg,
    const unsigned long long* __restrict__ zbuf,
    const float* __restrict__ src_img, float* __restrict__ out, int B)
{
    int idx = blockIdx.x * 256 + threadIdx.x;
    if (idx >= B * HH * WW) return;
    int b = idx >> 16;
    int pix = idx & 65535;
    int pxi = pix & 255, pyi = pix >> 8;
    float px = pixc(pxi), py = pixc(pyi);

    unsigned int fid = (unsigned int)zbuf[idx];
    float fx, fy;
    if (fid != 0xFFFFFFFFu) {
        const float* r = rast64 + ((size_t)b * RASTN + fid) * 16;
        float dx = __fsub_rn(px, r[0]);
        float dy = __fsub_rn(py, r[1]);
        float w0 = __fmul_rn(__fadd_rn(__fmul_rn(r[2], dx), __fmul_rn(r[3], dy)), r[6]);
        float w1 = __fmul_rn(__fadd_rn(__fmul_rn(r[4], dx), __fmul_rn(r[5], dy)), r[6]);
        float w2 = __fsub_rn(__fsub_rn(1.0f, w0), w1);
        const float4* fg = flowg + ((size_t)b * NFACES + fid) * 2;
        float4 g0 = fg[0];
        float4 g1 = fg[1];
        fx = __fadd_rn(__fadd_rn(__fmul_rn(w0, g0.x), __fmul_rn(w1, g0.z)),
                       __fmul_rn(w2, g1.x));
        fy = __fadd_rn(__fadd_rn(__fmul_rn(w0, g0.y), __fmul_rn(w1, g0.w)),
                       __fmul_rn(w2, g1.y));
    } else {
        fx = -2.0f; fy = -2.0f;
    }

    float ix = __fmul_rn(__fsub_rn(__fmul_rn(__fadd_rn(fx, 1.0f), 256.0f), 1.0f), 0.5f);
    float iy = __fmul_rn(__fsub_rn(__fmul_rn(__fadd_rn(fy, 1.0f), 256.0f), 1.0f), 0.5f);
    ix = fminf(fmaxf(ix, 0.0f), 255.0f);
    iy = fminf(fmaxf(iy, 0.0f), 255.0f);
    float x0f = floorf(ix), y0f = floorf(iy);
    float wx = __fsub_rn(ix, x0f), wy = __fsub_rn(iy, y0f);
    int x0i = (int)x0f, y0i = (int)y0f;
    int x1i = min(x0i + 1, 255), y1i = min(y0i + 1, 255);
    float omwx = __fsub_rn(1.0f, wx), omwy = __fsub_rn(1.0f, wy);
    float wa = __fmul_rn(omwx, omwy);
    float wb = __fmul_rn(wx, omwy);
    float wc = __fmul_rn(omwx, wy);
    float wd = __fmul_rn(wx, wy);
    const float* img = src_img + (size_t)b * 3 * HH * WW;
    int o00 = y0i * WW + x0i, o01 = y0i * WW + x1i;
    int o10 = y1i * WW + x0i, o11 = y1i * WW + x1i;
    float* ob = out + (size_t)b * 3 * HH * WW + (size_t)pyi * WW + pxi;
    for (int c = 0; c < 3; ++c) {
        const float* ic = img + (size_t)c * HH * WW;
        float Ia = ic[o00], Ib = ic[o01], Ic = ic[o10], Id = ic[o11];
        float val = __fadd_rn(__fadd_rn(__fadd_rn(__fmul_rn(Ia, wa), __fmul_rn(Ib, wb)),
                                        __fmul_rn(Ic, wc)),
                              __fmul_rn(Id, wd));
        ob[(size_t)c * HH * WW] = val;
    }
}

extern "C" void kernel_launch(void* const* d_in, const int* in_sizes, int n_in,
                              void* d_out, int out_size, void* d_ws, size_t ws_size,
                              hipStream_t stream)
{
    const float* src_img   = (const float*)d_in[0];
    const float* src_cam   = (const float*)d_in[1];
    const float* src_verts = (const float*)d_in[2];
    const float* tgt_cam   = (const float*)d_in[3];
    const float* tgt_verts = (const float*)d_in[4];
    const int*   faces     = (const int*)d_in[5];
    int B = in_sizes[1] / 3;   // src_cam is [B,3]

    size_t off = 0;
    auto alloc = [&](size_t bytes) {
        size_t o = off;
        off = (off + bytes + 255) & ~(size_t)255;
        return o;
    };
    size_t rastOff = alloc((size_t)B * RASTN * 64);
    size_t bbOff   = alloc((size_t)B * NFACES * sizeof(float4));
    size_t flowOff = alloc((size_t)B * NFACES * 2 * sizeof(float4));
    size_t zbufOff = alloc((size_t)B * HH * WW * sizeof(unsigned long long));
    size_t cntOff  = alloc((size_t)B * 256 * sizeof(int));
    size_t donOff  = alloc((size_t)B * 256 * sizeof(int));
    size_t qcOff   = alloc(sizeof(int));
    size_t quOff   = alloc((size_t)B * 256 * MAXCH * sizeof(unsigned int));
    size_t listOff = alloc((size_t)B * 256 * LISTSTRIDE * sizeof(int));
    bool binned = (off <= ws_size);

    char* ws = (char*)d_ws;
    float4* rast64 = (float4*)(ws + rastOff);
    float4* bbox   = (float4*)(ws + bbOff);
    float4* flowg  = (float4*)(ws + flowOff);
    unsigned long long* zbuf = (unsigned long long*)(ws + zbufOff);
    int* counts = binned ? (int*)(ws + cntOff) : nullptr;
    int* done   = binned ? (int*)(ws + donOff) : nullptr;
    int* qcount = binned ? (int*)(ws + qcOff)  : nullptr;
    unsigned int* queue = binned ? (unsigned int*)(ws + quOff) : nullptr;
    int* lists  = binned ? (int*)(ws + listOff) : nullptr;

    int nInit = B * HH * WW;
    int nPre  = B * RASTN;
    int nMax  = nInit > nPre ? nInit : nPre;
    precompute_kernel<<<(nMax + 255) / 256, 256, 0, stream>>>(
        src_cam, src_verts, tgt_cam, tgt_verts, faces,
        rast64, bbox, flowg, zbuf, counts, done, qcount, B);
    if (binned) {
        bin_kernel<<<dim3(256, SLABS, B), 256, 0, stream>>>(
            bbox, lists, counts, done, queue, qcount, B);
    }
    raster_kernel<<<NBLK, 256, 0, stream>>>(
        (const float*)rast64, lists, queue, qcount, zbuf, B);
    resolve_kernel<<<(B * HH * WW + 255) / 256, 256, 0, stream>>>(
        (const float*)rast64, flowg, zbuf, src_img, (float*)d_out, B);
}

// Round 9
// 204.467 us; speedup vs baseline: 6.0203x; 1.1208x over previous
//
#include <hip/hip_runtime.h>

#pragma clang fp contract(off)

#define HH 256
#define WW 256
#define NVERTS 6890
#define NFACES 13776
#define RASTN (NFACES + 1)          // +1 sentinel record (depth=BIG, never wins)
#define LISTSTRIDE 13824            // multiple of 128, >= NFACES
#define RCHUNK 128                  // faces per work item (one wave)
#define MAXCH 108                   // LISTSTRIDE / RCHUNK
#define SLABS 4                     // bin blocks per tile
#define WSUB 896                    // faces per wave (14 x 64)
#define NITER 14
#define SLABSZ (4 * WSUB)           // 3584 faces per block; 4 slabs >= NFACES
#define NBLK 1024                   // persistent raster blocks (x4 waves)
#define NWAVES (NBLK * 4)
#define BIGF 1000000000.0f
#define EPSF 1e-8f

// c(i) = ((i+0.5)/256)*2 - 1  -- exact in f32, matches reference pixel coords
__device__ __forceinline__ float pixc(int i) {
    return __fsub_rn(__fmul_rn(__fdiv_rn(__fadd_rn((float)i, 0.5f), 256.0f), 2.0f), 1.0f);
}

// order-preserving float->uint (all finite values, negatives included)
__device__ __forceinline__ unsigned int fsort(float f) {
    unsigned int u = __float_as_uint(f);
    return (u & 0x80000000u) ? ~u : (u | 0x80000000u);
}

// 64-B face record layout (floats):
// [0]=x2 [1]=y2 [2]=A [3]=B [4]=C [5]=D [6]=inv [7]=fid [8]=z0 [9]=z1 [10]=z2
// Degenerate / sentinel: A=B=C=D=0, inv=1 -> w0=w1=0,w2=1, depth = exactly BIG
// -> never wins strict-<, identical to ref's inside &= |denom|>=EPS.

// ---------------------------------------------------------------------------
// Kernel 1: precompute 64-B records + conservative bbox + flow verts; zbuf
// init; control zero-init.
// bbox = vertex bbox inflated by  E + slop + 1e-4  where
//   slop = 32eps * S   (perpendicular rounding slop of the rounded
//                       inside-test, denom-independent)
//   E = slop * max(|ei||ej|) / |denom|   (along-sliver extension:
//       computed-inside region of near-parallel edge pairs is a strip
//       ~slop/sin(phi), sin(phi) = |denom|/(|ei||ej|))
// Invalid faces (|denom|<EPS): empty bbox -> excluded from all lists (they
// can never win the strict-< z-test in the reference either).
// ---------------------------------------------------------------------------
__global__ __launch_bounds__(256) void precompute_kernel(
    const float* __restrict__ src_cam, const float* __restrict__ src_verts,
    const float* __restrict__ tgt_cam, const float* __restrict__ tgt_verts,
    const int* __restrict__ faces,
    float4* __restrict__ rast64, float4* __restrict__ bbox,
    float4* __restrict__ flowg,
    unsigned long long* __restrict__ zbuf,
    int* __restrict__ counts, int* __restrict__ done, int* __restrict__ qcount,
    int B)
{
    int idx = blockIdx.x * blockDim.x + threadIdx.x;
    if (idx < B * HH * WW) zbuf[idx] = ~0ull;   // background sentinel
    if (counts && idx < B * 256) { counts[idx] = 0; done[idx] = 0; }
    if (qcount && idx == 0) qcount[0] = 0;
    if (idx >= B * RASTN) return;
    int b = idx / RASTN;
    int f = idx - b * RASTN;
    float4* rr = rast64 + ((size_t)b * RASTN + f) * 4;
    if (f == NFACES) {   // sentinel record
        rr[0] = make_float4(0.0f, 0.0f, 0.0f, 0.0f);
        rr[1] = make_float4(0.0f, 0.0f, 1.0f, __int_as_float(-1));
        rr[2] = make_float4(BIGF, BIGF, BIGF, 0.0f);
        rr[3] = make_float4(0.0f, 0.0f, 0.0f, 0.0f);
        return;
    }
    int i0 = faces[3*f+0], i1 = faces[3*f+1], i2 = faces[3*f+2];

    float tc0 = tgt_cam[3*b+0], tc1 = tgt_cam[3*b+1], tc2 = tgt_cam[3*b+2];
    const float* tv = tgt_verts + (size_t)b * NVERTS * 3;
    float x0 = __fmul_rn(tc0, __fadd_rn(tv[3*i0+0], tc1));
    float y0 = -__fmul_rn(tc0, __fadd_rn(tv[3*i0+1], tc2));
    float z0 = tv[3*i0+2];
    float x1 = __fmul_rn(tc0, __fadd_rn(tv[3*i1+0], tc1));
    float y1 = -__fmul_rn(tc0, __fadd_rn(tv[3*i1+1], tc2));
    float z1 = tv[3*i1+2];
    float x2 = __fmul_rn(tc0, __fadd_rn(tv[3*i2+0], tc1));
    float y2 = -__fmul_rn(tc0, __fadd_rn(tv[3*i2+1], tc2));
    float z2 = tv[3*i2+2];

    float A  = __fsub_rn(y1, y2);
    float D  = __fsub_rn(x0, x2);
    float Bc = __fsub_rn(x2, x1);
    float E_ = __fsub_rn(y0, y2);
    float denom = __fadd_rn(__fmul_rn(A, D), __fmul_rn(Bc, E_));
    bool valid = (fabsf(denom) >= EPSF);
    float inv = __fdiv_rn(1.0f, valid ? denom : 1.0f);
    float Cc = __fsub_rn(y2, y0);

    if (valid) {
        rr[0] = make_float4(x2, y2, A, Bc);
        rr[1] = make_float4(Cc, D, inv, __int_as_float(f));
        rr[2] = make_float4(z0, z1, z2, 0.0f);
    } else {
        rr[0] = make_float4(0.0f, 0.0f, 0.0f, 0.0f);
        rr[1] = make_float4(0.0f, 0.0f, 1.0f, __int_as_float(f));
        rr[2] = make_float4(BIGF, BIGF, BIGF, 0.0f);
    }
    rr[3] = make_float4(0.0f, 0.0f, 0.0f, 0.0f);

    // conservative bbox
    float4 bb;
    if (valid) {
        float xmn = fminf(fminf(x0, x1), x2), xmx = fmaxf(fmaxf(x0, x1), x2);
        float ymn = fminf(fminf(y0, y1), y2), ymx = fmaxf(fmaxf(y0, y1), y2);
        float S = fmaxf(fmaxf(fabsf(xmn), fabsf(xmx)),
                        fmaxf(fabsf(ymn), fabsf(ymx))) + 1.01f;
        float slop = 2e-6f * S;                       // ~32 eps * S
        float l0 = sqrtf(D*D + E_*E_);                // |v0-v2|
        float dx1v = x1 - x2, dy1v = y1 - y2;
        float l1 = sqrtf(dx1v*dx1v + dy1v*dy1v);      // |v1-v2|
        float dx2v = x1 - x0, dy2v = y1 - y0;
        float l2 = sqrtf(dx2v*dx2v + dy2v*dy2v);      // |v1-v0|
        float mp = fmaxf(fmaxf(l0*l1, l1*l2), l0*l2);
        float Ex = slop * mp / fabsf(denom);          // sliver extension
        float m = Ex + slop + 1e-4f;
        bb = make_float4(xmn - m, ymn - m, xmx + m, ymx + m);
    } else {
        bb = make_float4(2e9f, 2e9f, -2e9f, -2e9f);   // empty
    }
    bbox[(size_t)b * NFACES + f] = bb;

    float sc0 = src_cam[3*b+0], sc1 = src_cam[3*b+1], sc2 = src_cam[3*b+2];
    const float* sv = src_verts + (size_t)b * NVERTS * 3;
    float g0x = __fmul_rn(sc0, __fadd_rn(sv[3*i0+0], sc1));
    float g0y = __fmul_rn(sc0, __fadd_rn(sv[3*i0+1], sc2));
    float g1x = __fmul_rn(sc0, __fadd_rn(sv[3*i1+0], sc1));
    float g1y = __fmul_rn(sc0, __fadd_rn(sv[3*i1+1], sc2));
    float g2x = __fmul_rn(sc0, __fadd_rn(sv[3*i2+0], sc1));
    float g2y = __fmul_rn(sc0, __fadd_rn(sv[3*i2+1], sc2));
    size_t fo = ((size_t)b * NFACES + f) * 2;
    flowg[fo+0] = make_float4(g0x, g0y, g1x, g1y);
    flowg[fo+1] = make_float4(g2x, g2y, 0.0f, 0.0f);
}

// ---------------------------------------------------------------------------
// Kernel 2: bin. Per-wave LDS-buffered compaction: the cull loop has ZERO
// global atomics (append offsets from ballot+popc against a REGISTER
// counter), so it pipelines on coalesced bbox loads. One global atomicAdd
// per wave (8192 total vs ~110k before -> kills the L2 same-line atomic
// serialization that made R8's bin 87us at 5% VALUBusy), then a coalesced
// segment dump. Order-independent (raster merge is an atomicMin). The LAST
// finishing slab (device-scope done counter) pads the list to x128 with the
// sentinel face and enqueues (tileG,chunk) work items.
// ---------------------------------------------------------------------------
__global__ __launch_bounds__(256) void bin_kernel(
    const float4* __restrict__ bbox, int* __restrict__ lists,
    int* __restrict__ counts, int* __restrict__ done,
    unsigned int* __restrict__ queue, int* __restrict__ qcount, int B)
{
    __shared__ int seg[4][WSUB];
    int tile = blockIdx.x;          // 0..255
    int slab = blockIdx.y;
    int b = blockIdx.z;
    int tileG = b * 256 + tile;
    int tX = tile & 15, tY = tile >> 4;
    float txmin = pixc(tX * 16), txmax = pixc(tX * 16 + 15);
    float tymin = pixc(tY * 16), tymax = pixc(tY * 16 + 15);

    int wv = threadIdx.x >> 6, lane = threadIdx.x & 63;
    const float4* bbs = bbox + (size_t)b * NFACES;
    int* mylist = lists + (size_t)tileG * LISTSTRIDE;
    int wlo = slab * SLABSZ + wv * WSUB;
    int cnt = 0;

    #pragma unroll
    for (int it = 0; it < NITER; ++it) {
        int f = wlo + it * 64 + lane;
        bool pass = false;
        if (f < NFACES) {
            float4 bb = bbs[f];
            pass = (bb.x <= txmax) & (bb.z >= txmin) &
                   (bb.y <= tymax) & (bb.w >= tymin);
        }
        unsigned long long m = __ballot(pass);
        if (pass) {
            int pre = __popcll(m & ((1ull << lane) - 1ull));
            seg[wv][cnt + pre] = f;
        }
        cnt += __popcll(m);
    }

    int gbase = 0;
    if (lane == 0 && cnt) gbase = atomicAdd(&counts[tileG], cnt);
    gbase = __shfl(gbase, 0);
    for (int i = lane; i < cnt; i += 64) mylist[gbase + i] = seg[wv][i];

    __syncthreads();
    if (threadIdx.x == 0) {
        __threadfence();                      // counts/list writes visible
        if (atomicAdd(&done[tileG], 1) == SLABS - 1) {
            int c = atomicAdd(&counts[tileG], 0);     // coherent read
            int padded = (c + RCHUNK - 1) & ~(RCHUNK - 1);
            for (int i = c; i < padded; ++i) mylist[i] = NFACES;
            int nch = padded >> 7;
            if (nch) {
                int qb = atomicAdd(qcount, nch);
                for (int kk = 0; kk < nch; ++kk)
                    queue[qb + kk] = ((unsigned int)tileG << 8) | (unsigned int)kk;
            }
        }
    }
}

// ---------------------------------------------------------------------------
// Kernel 3: raster. 4096 persistent waves grid-stride the work queue; each
// entry = (tileG, 128-face chunk). NO LDS: face indices load as uniform int4
// (scalar pipe), face records as uniform 64-B s_loads from rast64 (fid
// embedded). Each lane owns 4 pixels of the 16x16 tile sharing one column
// (dx, A*dx, C*dx computed once per face, bit-identical reuse). Per-pixel
// u64 atomicMin of (sortable_depth, fid) == exact lexicographic min ==
// reference's first-argmin + strict-< semantics. All depth math _rn,
// no FMA contraction -> bit-identical to the f32 reference.
// ---------------------------------------------------------------------------
__global__ __launch_bounds__(256) void raster_kernel(
    const float* __restrict__ rast64, const int* __restrict__ lists,
    const unsigned int* __restrict__ queue, const int* __restrict__ qcount,
    unsigned long long* __restrict__ zbuf, int B)
{
    int wv = threadIdx.x >> 6, lane = threadIdx.x & 63;
    int waveId = blockIdx.x * 4 + wv;
    int qn = queue ? qcount[0] : B * 256 * MAXCH;
    qn = __builtin_amdgcn_readfirstlane(qn);

    for (int e = waveId; e < qn; e += NWAVES) {
        int tileG, k;
        if (queue) {
            unsigned int ent = queue[e];
            tileG = (int)(ent >> 8); k = (int)(ent & 255u);
        } else {
            tileG = e / MAXCH; k = e - tileG * MAXCH;
        }
        tileG = __builtin_amdgcn_readfirstlane(tileG);
        k = __builtin_amdgcn_readfirstlane(k);
        int b = tileG >> 8, tile = tileG & 255;
        const int* lp = lists ? (lists + (size_t)tileG * LISTSTRIDE + k * RCHUNK)
                              : nullptr;
        const float* rb = rast64 + (size_t)b * RASTN * 16;

        int tX = tile & 15, tY = tile >> 4;
        int col = lane & 15, row0 = lane >> 4;
        int pxi = tX * 16 + col;
        float px = pixc(pxi);
        float py0 = pixc(tY * 16 + row0);
        float py1 = pixc(tY * 16 + row0 + 4);
        float py2 = pixc(tY * 16 + row0 + 8);
        float py3 = pixc(tY * 16 + row0 + 12);

        float z0c = BIGF, z1c = BIGF, z2c = BIGF, z3c = BIGF;
        int f0c = -1, f1c = -1, f2c = -1, f3c = -1;

        for (int j = 0; j < RCHUNK; j += 4) {
            int4 fis;
            if (lp) {
                fis = *(const int4*)(lp + j);
            } else {
                int base = k * RCHUNK + j;
                fis.x = min(base + 0, NFACES); fis.y = min(base + 1, NFACES);
                fis.z = min(base + 2, NFACES); fis.w = min(base + 3, NFACES);
            }
            #pragma unroll
            for (int q = 0; q < 4; ++q) {
                int fi = (q == 0) ? fis.x : (q == 1) ? fis.y : (q == 2) ? fis.z : fis.w;
                fi = __builtin_amdgcn_readfirstlane(fi);
                const float* r = rb + (size_t)fi * 16;
                float X2 = r[0], Y2 = r[1], A = r[2], Bc = r[3];
                float Cc = r[4], Dd = r[5], inv = r[6];
                int   fid = __float_as_int(r[7]);
                float Z0 = r[8], Z1 = r[9], Z2 = r[10];

                float dx  = __fsub_rn(px, X2);
                float Adx = __fmul_rn(A, dx);
                float Cdx = __fmul_rn(Cc, dx);
                auto evalp = [&](float py, float& zc, int& fc) {
                    float dy = __fsub_rn(py, Y2);
                    float w0 = __fmul_rn(__fadd_rn(Adx, __fmul_rn(Bc, dy)), inv);
                    float w1 = __fmul_rn(__fadd_rn(Cdx, __fmul_rn(Dd, dy)), inv);
                    float w2 = __fsub_rn(__fsub_rn(1.0f, w0), w1);
                    float d  = __fadd_rn(__fadd_rn(__fmul_rn(w0, Z0), __fmul_rn(w1, Z1)),
                                         __fmul_rn(w2, Z2));
                    float mm = fminf(fminf(w0, w1), w2);    // v_min3
                    bool ins = (mm >= 0.0f) & (d < zc);
                    if (ins) { zc = d; fc = fid; }
                };
                evalp(py0, z0c, f0c);
                evalp(py1, z1c, f1c);
                evalp(py2, z2c, f2c);
                evalp(py3, z3c, f3c);
            }
        }

        auto commit = [&](int rowk, float zc, int fc) {
            if (fc >= 0) {
                unsigned long long pk =
                    ((unsigned long long)fsort(zc) << 32) | (unsigned int)fc;
                int pyi = tY * 16 + row0 + rowk * 4;
                atomicMin(&zbuf[((size_t)b << 16) | (pyi << 8) | pxi], pk);
            }
        };
        commit(0, z0c, f0c);
        commit(1, z1c, f1c);
        commit(2, z2c, f2c);
        commit(3, z3c, f3c);
    }
}

// ---------------------------------------------------------------------------
// Kernel 4: resolve. Per pixel: read winning fid, recompute w0,w1 from the
// record (same _rn sequence -> bit-identical), flow gather, bilinear sample.
// ---------------------------------------------------------------------------
__global__ __launch_bounds__(256) void resolve_kernel(
    const float* __restrict__ rast64, const float4* __restrict__ flowg,
    const unsigned long long* __restrict__ zbuf,
    const float* __restrict__ src_img, float* __restrict__ out, int B)
{
    int idx = blockIdx.x * 256 + threadIdx.x;
    if (idx >= B * HH * WW) return;
    int b = idx >> 16;
    int pix = idx & 65535;
    int pxi = pix & 255, pyi = pix >> 8;
    float px = pixc(pxi), py = pixc(pyi);

    unsigned int fid = (unsigned int)zbuf[idx];
    float fx, fy;
    if (fid != 0xFFFFFFFFu) {
        const float* r = rast64 + ((size_t)b * RASTN + fid) * 16;
        float dx = __fsub_rn(px, r[0]);
        float dy = __fsub_rn(py, r[1]);
        float w0 = __fmul_rn(__fadd_rn(__fmul_rn(r[2], dx), __fmul_rn(r[3], dy)), r[6]);
        float w1 = __fmul_rn(__fadd_rn(__fmul_rn(r[4], dx), __fmul_rn(r[5], dy)), r[6]);
        float w2 = __fsub_rn(__fsub_rn(1.0f, w0), w1);
        const float4* fg = flowg + ((size_t)b * NFACES + fid) * 2;
        float4 g0 = fg[0];
        float4 g1 = fg[1];
        fx = __fadd_rn(__fadd_rn(__fmul_rn(w0, g0.x), __fmul_rn(w1, g0.z)),
                       __fmul_rn(w2, g1.x));
        fy = __fadd_rn(__fadd_rn(__fmul_rn(w0, g0.y), __fmul_rn(w1, g0.w)),
                       __fmul_rn(w2, g1.y));
    } else {
        fx = -2.0f; fy = -2.0f;
    }

    float ix = __fmul_rn(__fsub_rn(__fmul_rn(__fadd_rn(fx, 1.0f), 256.0f), 1.0f), 0.5f);
    float iy = __fmul_rn(__fsub_rn(__fmul_rn(__fadd_rn(fy, 1.0f), 256.0f), 1.0f), 0.5f);
    ix = fminf(fmaxf(ix, 0.0f), 255.0f);
    iy = fminf(fmaxf(iy, 0.0f), 255.0f);
    float x0f = floorf(ix), y0f = floorf(iy);
    float wx = __fsub_rn(ix, x0f), wy = __fsub_rn(iy, y0f);
    int x0i = (int)x0f, y0i = (int)y0f;
    int x1i = min(x0i + 1, 255), y1i = min(y0i + 1, 255);
    float omwx = __fsub_rn(1.0f, wx), omwy = __fsub_rn(1.0f, wy);
    float wa = __fmul_rn(omwx, omwy);
    float wb = __fmul_rn(wx, omwy);
    float wc = __fmul_rn(omwx, wy);
    float wd = __fmul_rn(wx, wy);
    const float* img = src_img + (size_t)b * 3 * HH * WW;
    int o00 = y0i * WW + x0i, o01 = y0i * WW + x1i;
    int o10 = y1i * WW + x0i, o11 = y1i * WW + x1i;
    float* ob = out + (size_t)b * 3 * HH * WW + (size_t)pyi * WW + pxi;
    for (int c = 0; c < 3; ++c) {
        const float* ic = img + (size_t)c * HH * WW;
        float Ia = ic[o00], Ib = ic[o01], Ic = ic[o10], Id = ic[o11];
        float val = __fadd_rn(__fadd_rn(__fadd_rn(__fmul_rn(Ia, wa), __fmul_rn(Ib, wb)),
                                        __fmul_rn(Ic, wc)),
                              __fmul_rn(Id, wd));
        ob[(size_t)c * HH * WW] = val;
    }
}

extern "C" void kernel_launch(void* const* d_in, const int* in_sizes, int n_in,
                              void* d_out, int out_size, void* d_ws, size_t ws_size,
                              hipStream_t stream)
{
    const float* src_img   = (const float*)d_in[0];
    const float* src_cam   = (const float*)d_in[1];
    const float* src_verts = (const float*)d_in[2];
    const float* tgt_cam   = (const float*)d_in[3];
    const float* tgt_verts = (const float*)d_in[4];
    const int*   faces     = (const int*)d_in[5];
    int B = in_sizes[1] / 3;   // src_cam is [B,3]

    size_t off = 0;
    auto alloc = [&](size_t bytes) {
        size_t o = off;
        off = (off + bytes + 255) & ~(size_t)255;
        return o;
    };
    size_t rastOff = alloc((size_t)B * RASTN * 64);
    size_t bbOff   = alloc((size_t)B * NFACES * sizeof(float4));
    size_t flowOff = alloc((size_t)B * NFACES * 2 * sizeof(float4));
    size_t zbufOff = alloc((size_t)B * HH * WW * sizeof(unsigned long long));
    size_t cntOff  = alloc((size_t)B * 256 * sizeof(int));
    size_t donOff  = alloc((size_t)B * 256 * sizeof(int));
    size_t qcOff   = alloc(sizeof(int));
    size_t quOff   = alloc((size_t)B * 256 * MAXCH * sizeof(unsigned int));
    size_t listOff = alloc((size_t)B * 256 * LISTSTRIDE * sizeof(int));
    bool binned = (off <= ws_size);

    char* ws = (char*)d_ws;
    float4* rast64 = (float4*)(ws + rastOff);
    float4* bbox   = (float4*)(ws + bbOff);
    float4* flowg  = (float4*)(ws + flowOff);
    unsigned long long* zbuf = (unsigned long long*)(ws + zbufOff);
    int* counts = binned ? (int*)(ws + cntOff) : nullptr;
    int* done   = binned ? (int*)(ws + donOff) : nullptr;
    int* qcount = binned ? (int*)(ws + qcOff)  : nullptr;
    unsigned int* queue = binned ? (unsigned int*)(ws + quOff) : nullptr;
    int* lists  = binned ? (int*)(ws + listOff) : nullptr;

    int nInit = B * HH * WW;
    int nPre  = B * RASTN;
    int nMax  = nInit > nPre ? nInit : nPre;
    precompute_kernel<<<(nMax + 255) / 256, 256, 0, stream>>>(
        src_cam, src_verts, tgt_cam, tgt_verts, faces,
        rast64, bbox, flowg, zbuf, counts, done, qcount, B);
    if (binned) {
        bin_kernel<<<dim3(256, SLABS, B), 256, 0, stream>>>(
            bbox, lists, counts, done, queue, qcount, B);
    }
    raster_kernel<<<NBLK, 256, 0, stream>>>(
        (const float*)rast64, lists, queue, qcount, zbuf, B);
    resolve_kernel<<<(B * HH * WW + 255) / 256, 256, 0, stream>>>(
        (const float*)rast64, flowg, zbuf, src_img, (float*)d_out, B);
}